// Round 17
// baseline (232.910 us; speedup 1.0000x reference)
//
#include <hip/hip_runtime.h>

typedef __attribute__((ext_vector_type(8))) __bf16 bf16x8;
typedef __attribute__((ext_vector_type(4))) float f32x4;
typedef __attribute__((ext_vector_type(8))) unsigned short u16x8;
typedef __attribute__((ext_vector_type(4))) unsigned short u16x4;
typedef unsigned short u16;

__device__ __forceinline__ u16 f2bf(float f) {
  return __builtin_bit_cast(u16, (__bf16)f);
}
__device__ __forceinline__ float bf2f(u16 u) {
  return __builtin_bit_cast(float, ((unsigned)u) << 16);
}

__device__ __forceinline__ f32x4 mfma16(bf16x8 a, bf16x8 b, f32x4 c) {
  return __builtin_amdgcn_mfma_f32_16x16x32_bf16(a, b, c, 0, 0, 0);
}

__device__ __forceinline__ void gl_lds16(const void* g, void* l) {
  __builtin_amdgcn_global_load_lds(
      (const __attribute__((address_space(1))) unsigned int*)g,
      (__attribute__((address_space(3))) unsigned int*)l, 16, 0, 0);
}

__device__ __forceinline__ f32x4 fmax4(f32x4 a, f32x4 b) {
  f32x4 r;
  r[0] = fmaxf(a[0], b[0]); r[1] = fmaxf(a[1], b[1]);
  r[2] = fmaxf(a[2], b[2]); r[3] = fmaxf(a[3], b[3]);
  return r;
}

// ---- batched transpose+convert: 3 weight jobs in one launch -------------------------
__global__ __launch_bounds__(256) void convT_all(const float* __restrict__ w0,
                                                 u16* __restrict__ o0,
                                                 const float* __restrict__ w1,
                                                 u16* __restrict__ o1,
                                                 const float* __restrict__ w2,
                                                 u16* __restrict__ o2) {
  __shared__ float tile[64][65];
  const int id = blockIdx.x;
  const float* in;
  u16* outT;
  int K, N, bx, by;
  if (id < 768) { in = w0; outT = o0; K = 1024; N = 3072; bx = id & 15; by = id >> 4; }
  else if (id < 1024) { const int j = id - 768; in = w1; outT = o1; K = 1024; N = 1024; bx = j & 15; by = j >> 4; }
  else { const int j = id - 1024; in = w2; outT = o2; K = 1024; N = 4096; bx = j & 15; by = j >> 4; }
  const int t = threadIdx.x;
  const int tk = bx * 64, tn = by * 64;
  const int lk = t >> 4, ln = (t & 15) * 4;
#pragma unroll
  for (int r = 0; r < 4; ++r) {
    const int k = lk + r * 16;
    const float4 v = *(const float4*)(in + (size_t)(tk + k) * N + tn + ln);
    tile[k][ln + 0] = v.x; tile[k][ln + 1] = v.y;
    tile[k][ln + 2] = v.z; tile[k][ln + 3] = v.w;
  }
  __syncthreads();
  const int sn = t >> 2, sk = (t & 3) * 4;
#pragma unroll
  for (int j = 0; j < 4; ++j) {
    const int k = sk + j * 16;
    ushort4 o;
    o.x = f2bf(tile[k + 0][sn]); o.y = f2bf(tile[k + 1][sn]);
    o.z = f2bf(tile[k + 2][sn]); o.w = f2bf(tile[k + 3][sn]);
    *(ushort4*)(outT + (size_t)(tn + sn) * K + tk + k) = o;
  }
}

// ---------------- single transpose+convert (wcproj, mid-pipeline) --------------------
__global__ __launch_bounds__(256) void convT(const float* __restrict__ in,
                                             u16* __restrict__ outT, int K, int N) {
  __shared__ float tile[64][65];
  const int t = threadIdx.x;
  const int tk = blockIdx.x * 64, tn = blockIdx.y * 64;
  const int lk = t >> 4, ln = (t & 15) * 4;
#pragma unroll
  for (int r = 0; r < 4; ++r) {
    const int k = lk + r * 16;
    const float4 v = *(const float4*)(in + (size_t)(tk + k) * N + tn + ln);
    tile[k][ln + 0] = v.x; tile[k][ln + 1] = v.y;
    tile[k][ln + 2] = v.z; tile[k][ln + 3] = v.w;
  }
  __syncthreads();
  const int sn = t >> 2, sk = (t & 3) * 4;
#pragma unroll
  for (int j = 0; j < 4; ++j) {
    const int k = sk + j * 16;
    ushort4 o;
    o.x = f2bf(tile[k + 0][sn]); o.y = f2bf(tile[k + 1][sn]);
    o.z = f2bf(tile[k + 2][sn]); o.w = f2bf(tile[k + 3][sn]);
    *(ushort4*)(outT + (size_t)(tn + sn) * K + tk + k) = o;
  }
}

// ---- V transpose (bf16): vT[bh][dh][t] = qkv[b*2048+t][2048 + h*64 + dh] ------------
__global__ __launch_bounds__(256) void vtrans(const u16* __restrict__ qkvb,
                                              u16* __restrict__ vT) {
  __shared__ u16 tile[64][72];
  const int t = threadIdx.x;
  const int tt0 = blockIdx.x * 64;
  const int bh = blockIdx.y;
  const int b = bh >> 4, h = bh & 15;
  const u16* src = qkvb + (size_t)(b * 2048 + tt0) * 3072 + 2048 + h * 64;
  {
    const int tl = t >> 2, d0 = (t & 3) * 16;
    const u16x8 a0 = *(const u16x8*)(src + (size_t)tl * 3072 + d0);
    const u16x8 a1 = *(const u16x8*)(src + (size_t)tl * 3072 + d0 + 8);
    *(u16x8*)(&tile[tl][d0]) = a0;
    *(u16x8*)(&tile[tl][d0 + 8]) = a1;
  }
  __syncthreads();
  {
    const int dh = t >> 2, t0 = (t & 3) * 16;
    u16x8 o0, o1;
#pragma unroll
    for (int jj = 0; jj < 8; ++jj) {
      o0[jj] = tile[t0 + jj][dh];
      o1[jj] = tile[t0 + 8 + jj][dh];
    }
    u16* dst = vT + ((size_t)bh * 64 + dh) * 2048 + tt0 + t0;
    *(u16x8*)dst = o0;
    *(u16x8*)(dst + 8) = o1;
  }
}

// ---------------- LayerNorm (C=1024 fixed), fp32 in -> bf16 out ----------------------
__global__ __launch_bounds__(256) void ln_bf16(const float* __restrict__ x,
                                               const float* __restrict__ wgt,
                                               u16* __restrict__ out) {
  const int row = blockIdx.x, t = threadIdx.x;
  const float4 v = ((const float4*)(x + (size_t)row * 1024))[t];
  float s = v.x + v.y + v.z + v.w;
  float q = v.x * v.x + v.y * v.y + v.z * v.z + v.w * v.w;
#pragma unroll
  for (int d = 32; d; d >>= 1) { s += __shfl_xor(s, d); q += __shfl_xor(q, d); }
  __shared__ float sb[8];
  const int wv = t >> 6;
  if ((t & 63) == 0) { sb[wv] = s; sb[4 + wv] = q; }
  __syncthreads();
  s = sb[0] + sb[1] + sb[2] + sb[3];
  q = sb[4] + sb[5] + sb[6] + sb[7];
  const float mu = s * (1.f / 1024.f);
  const float rstd = rsqrtf(q * (1.f / 1024.f) - mu * mu + 1e-5f);
  const float4 w4 = ((const float4*)wgt)[t];
  ushort4 o;
  o.x = f2bf((v.x - mu) * rstd * w4.x);
  o.y = f2bf((v.y - mu) * rstd * w4.y);
  o.z = f2bf((v.z - mu) * rstd * w4.z);
  o.w = f2bf((v.w - mu) * rstd * w4.w);
  *(ushort4*)(out + (size_t)row * 1024 + t * 4) = o;
}

// ---- reduce_ln: x1 = x + sum(bf16 partials); h2 = LN(x1)*w. one block per row -------
__global__ __launch_bounds__(256) void reduce_ln(const float* __restrict__ x,
                                                 const u16* __restrict__ p, int nseg,
                                                 const float* __restrict__ wgt,
                                                 float* __restrict__ x1,
                                                 u16* __restrict__ h2) {
  const int row = blockIdx.x, t = threadIdx.x;
  const size_t ro = (size_t)row * 1024 + t * 4;
  float4 v = *(const float4*)(x + ro);
  for (int sgm = 0; sgm < nseg; ++sgm) {
    const ushort4 u = *(const ushort4*)(p + (size_t)sgm * 4096 * 1024 + ro);
    v.x += bf2f(u.x); v.y += bf2f(u.y); v.z += bf2f(u.z); v.w += bf2f(u.w);
  }
  *(float4*)(x1 + ro) = v;
  float s = v.x + v.y + v.z + v.w;
  float q = v.x * v.x + v.y * v.y + v.z * v.z + v.w * v.w;
#pragma unroll
  for (int d = 32; d; d >>= 1) { s += __shfl_xor(s, d); q += __shfl_xor(q, d); }
  __shared__ float sb[8];
  const int wv = t >> 6;
  if ((t & 63) == 0) { sb[wv] = s; sb[4 + wv] = q; }
  __syncthreads();
  s = sb[0] + sb[1] + sb[2] + sb[3];
  q = sb[4] + sb[5] + sb[6] + sb[7];
  const float mu = s * (1.f / 1024.f);
  const float rstd = rsqrtf(q * (1.f / 1024.f) - mu * mu + 1e-5f);
  const float4 w4 = ((const float4*)wgt)[t];
  ushort4 o;
  o.x = f2bf((v.x - mu) * rstd * w4.x);
  o.y = f2bf((v.y - mu) * rstd * w4.y);
  o.z = f2bf((v.z - mu) * rstd * w4.z);
  o.w = f2bf((v.w - mu) * rstd * w4.w);
  *(ushort4*)(h2 + ro) = o;
}

// ---- reduce_out: out = x1 + sum(bf16 partials). one float4 per thread ---------------
__global__ __launch_bounds__(256) void reduce_out(const float* __restrict__ x1,
                                                  const u16* __restrict__ p, int nseg,
                                                  float* __restrict__ out) {
  const int i = blockIdx.x * blockDim.x + threadIdx.x;
  const size_t ro = (size_t)i * 4;
  float4 v = *(const float4*)(x1 + ro);
  for (int sgm = 0; sgm < nseg; ++sgm) {
    const ushort4 u = *(const ushort4*)(p + (size_t)sgm * 4096 * 1024 + ro);
    v.x += bf2f(u.x); v.y += bf2f(u.y); v.z += bf2f(u.z); v.w += bf2f(u.w);
  }
  *(float4*)(out + ro) = v;
}

// ---------------- 128x128 bf16 MFMA GEMM (proj, split-K partials) --------------------
template <int EPI>
__global__ __launch_bounds__(256) void gemm128(const u16* __restrict__ A,
                                               const u16* __restrict__ Bt,
                                               void* __restrict__ outp,
                                               int M, int N, int K) {
  __shared__ u16 As[2][4096];
  __shared__ u16 Bs[2][4096];
  const unsigned gx = gridDim.x, gy = gridDim.y, gxy = gx * gy;
  const unsigned nwg = gxy * gridDim.z;
  unsigned f = (blockIdx.z * gy + blockIdx.y) * gx + blockIdx.x;
  if ((nwg & 7u) == 0u) { const unsigned qq = nwg >> 3; f = (f & 7u) * qq + (f >> 3); }
  const int bx = f % gx, by = (f / gx) % gy, bz = f / gxy;

  const int t = threadIdx.x, w = t >> 6, l = t & 63;
  const int lr = l & 15, g = l >> 4;
  const int row0 = by * 128, col0 = bx * 128;
  const int segK = K / gridDim.z;
  const int k0 = bz * segK, kend = k0 + segK;
  const int wr = w >> 1, wc = w & 1;
  f32x4 acc[4][4] = {};

  const int sr = t >> 2;
  const int sk = (((t & 3) ^ (sr & 3)) << 3);
  const u16* Ag = A + (size_t)(row0 + sr) * K + sk;
  const u16* Bg = Bt + (size_t)(col0 + sr) * K + sk;
  const size_t rstride = (size_t)64 * K;

  auto stage = [&](int kt, int bb) {
    u16* AsW = As[bb] + w * 512;
    u16* BsW = Bs[bb] + w * 512;
    gl_lds16(Ag + kt, AsW);
    gl_lds16(Ag + kt + rstride, AsW + 2048);
    gl_lds16(Bg + kt, BsW);
    gl_lds16(Bg + kt + rstride, BsW + 2048);
  };

  const int gsw = (g ^ (lr & 3)) * 8;

  stage(k0, 0);
  __syncthreads();
  int cur = 0;
  for (int kt = k0; kt < kend; kt += 32) {
    if (kt + 32 < kend) stage(kt + 32, cur ^ 1);
    bf16x8 af[4], bfr[4];
#pragma unroll
    for (int m = 0; m < 4; ++m)
      af[m] = *(const bf16x8*)(As[cur] + (wr * 64 + m * 16 + lr) * 32 + gsw);
#pragma unroll
    for (int n = 0; n < 4; ++n)
      bfr[n] = *(const bf16x8*)(Bs[cur] + (wc * 64 + n * 16 + lr) * 32 + gsw);
#pragma unroll
    for (int m = 0; m < 4; ++m)
#pragma unroll
      for (int n = 0; n < 4; ++n) acc[m][n] = mfma16(af[m], bfr[n], acc[m][n]);
    __syncthreads();
    cur ^= 1;
  }

  const size_t segoff = (size_t)bz * M * N;
#pragma unroll
  for (int m = 0; m < 4; ++m)
#pragma unroll
    for (int n = 0; n < 4; ++n)
#pragma unroll
      for (int r = 0; r < 4; ++r) {
        const int row = row0 + wr * 64 + m * 16 + g * 4 + r;
        const int col = col0 + wc * 64 + n * 16 + lr;
        const size_t idx = (size_t)row * N + col;
        const float v = acc[m][n][r];
        if constexpr (EPI == 0) ((u16*)outp)[idx] = f2bf(v);
        else if constexpr (EPI == 2) ((u16*)outp)[idx] = f2bf(fmaxf(v, 0.f));
        else ((u16*)outp)[segoff + idx] = f2bf(v);
      }
}

// ---------------- 256x256 8-phase bf16 GEMM (qkv / fc / cproj) — R15-verified --------
template <int EPI>
__global__ __launch_bounds__(512, 2) void gemm256(const u16* __restrict__ A,
                                                  const u16* __restrict__ Bt,
                                                  u16* __restrict__ outp,
                                                  int M, int N, int K) {
  __shared__ u16 S[2][32768];  // [buf][ A: kh0 0..8191, kh1 8192..16383 | B: +16384 ]
  const unsigned gx = gridDim.x, gy = gridDim.y, gxy = gx * gy;
  const unsigned nwg = gxy * gridDim.z;
  unsigned f = (blockIdx.z * gy + blockIdx.y) * gx + blockIdx.x;
  if ((nwg & 7u) == 0u) { const unsigned qq = nwg >> 3; f = (f & 7u) * qq + (f >> 3); }
  const int bx = f % gx, by = (f / gx) % gy, bz = f / gxy;
  const int t = threadIdx.x, w = t >> 6, l = t & 63;
  const int lr = l & 15, g = l >> 4;
  const int wr = w >> 2, wc = w & 3;
  const int row0 = by * 256, col0 = bx * 256;
  const int segK = K / gridDim.z;
  const int k0 = bz * segK;
  const int NT = segK >> 6;

  f32x4 acc[8][4] = {};

  const int jr0 = t >> 2;
  const int jr1 = jr0 + 128;
  const int jks = ((t & 3) ^ (jr0 & 3)) << 3;
  auto stage_half = [&](int ht, int idx) {
    const int buf = ht & 1;
    u16* db = &S[buf][(idx & 1) * 16384 + (idx >> 1) * 8192 + w * 512];
    const u16* gb = (idx & 1) ? Bt : A;
    const int rc0 = (idx & 1) ? col0 : row0;
    const int kb = k0 + ht * 64 + (idx >> 1) * 32;
    gl_lds16(gb + (size_t)(rc0 + jr0) * K + kb + jks, db);
    gl_lds16(gb + (size_t)(rc0 + jr1) * K + kb + jks, db + 4096);
  };

  const int gsw = (g ^ (lr & 3)) * 8;

  stage_half(0, 0); stage_half(0, 1); stage_half(0, 2); stage_half(0, 3);
  stage_half(1, 0); stage_half(1, 1);
  asm volatile("s_waitcnt vmcnt(4)" ::: "memory");
  __builtin_amdgcn_s_barrier();

  for (int T = 0; T < NT; ++T) {
    const int cur = T & 1;
    const u16* Ab = &S[cur][0];
    const u16* Bb = &S[cur][16384];
    bf16x8 bfr[4];
#pragma unroll
    for (int sub = 0; sub < 4; ++sub) {
      const int mq = sub & 1, ks = sub >> 1;
      if (mq == 0) {
#pragma unroll
        for (int n = 0; n < 4; ++n)
          bfr[n] = *(const bf16x8*)(Bb + ks * 8192 + (wc * 64 + n * 16 + lr) * 32 + gsw);
      }
      bf16x8 af[4];
#pragma unroll
      for (int m = 0; m < 4; ++m)
        af[m] = *(const bf16x8*)(Ab + ks * 8192 +
                                 (wr * 128 + mq * 64 + m * 16 + lr) * 32 + gsw);
      if (sub < 2) { if (T + 1 < NT) stage_half(T + 1, 2 + sub); }
      else         { if (T + 2 < NT) stage_half(T + 2, sub - 2); }
      __builtin_amdgcn_s_barrier();
      __builtin_amdgcn_s_setprio(1);
#pragma unroll
      for (int m = 0; m < 4; ++m)
#pragma unroll
        for (int n = 0; n < 4; ++n)
          acc[mq * 4 + m][n] = mfma16(af[m], bfr[n], acc[mq * 4 + m][n]);
      __builtin_amdgcn_s_setprio(0);
      if (sub == 3) asm volatile("s_waitcnt vmcnt(4)" ::: "memory");
      __builtin_amdgcn_s_barrier();
    }
  }

  const size_t segoff = (size_t)bz * M * N;
#pragma unroll
  for (int m = 0; m < 8; ++m)
#pragma unroll
    for (int n = 0; n < 4; ++n)
#pragma unroll
      for (int r = 0; r < 4; ++r) {
        const int row = row0 + wr * 128 + m * 16 + g * 4 + r;
        const int col = col0 + wc * 64 + n * 16 + lr;
        const size_t idx = (size_t)row * N + col;
        const float v = acc[m][n][r];
        if constexpr (EPI == 0) outp[idx] = f2bf(v);
        else if constexpr (EPI == 2) outp[idx] = f2bf(fmaxf(v, 0.f));
        else outp[segoff + idx] = f2bf(v);
      }
}

// ---------------- causal flash attention, bf16 MFMA, KV-SPLIT ------------------------
// R16 inner loop unchanged. qt>=15 computed by 2 blocks over half kv-ranges each
// (max 16 serial tiles, was 32); partials (unnormalized o, m, s) -> po/pm scratch,
// merged by attn_combine. qt<15: direct y write. Grid 1568 = 8 XCD x 196 jobs,
// longest jobs dispatched first, all q-tiles of one bh on one XCD.
__global__ __launch_bounds__(256) void attn_fwd(const u16* __restrict__ qkvb,
                                                const u16* __restrict__ vT,
                                                u16* __restrict__ y,
                                                float* __restrict__ po,
                                                float* __restrict__ pm) {
  __shared__ u16 Ks[2][4096];     // 2 x 8KB, swizzled rows [kv][k]
  __shared__ u16 Vs[2][4096];     // 2 x 8KB, swizzled rows [dh][kv]
  __shared__ u16 Pb[4][16 * 64];  // per-wave P: [q 0..15][kv 0..63], XOR-swizzled
  const int t = threadIdx.x, w = t >> 6, l = t & 63;
  const int lr = l & 15, g = l >> 4;
  // job decode: f&7 = xcd; per xcd 196 jobs = 4 bh x 49 (qt,seg) jobs, long-first
  const unsigned f = blockIdx.x;
  const int xcd = f & 7, j = f >> 3;
  const int bh = xcd + 8 * (j & 3);
  const int j2 = j >> 2;  // 0..48
  int qt, seg, split;
  if (j2 < 34) { qt = 31 - (j2 >> 1); seg = j2 & 1; split = 1; }
  else { qt = 48 - j2; seg = 0; split = 0; }
  const int nt0 = qt + 1;
  const int half = (nt0 + 1) >> 1;
  const int t_begin = (split && seg) ? half : 0;
  const int t_end = (split && !seg) ? half : nt0;
  const int b = bh >> 4, h = bh & 15;
  const size_t base = (size_t)b * 2048 * 3072;
  const u16* Kg = qkvb + base + 1024 + h * 64;
  const u16* Vg = vT + (size_t)bh * 64 * 2048;  // [dh][t]
  u16* Pw = &Pb[w][0];
  const int pkey = (lr & 7) << 3;         // P-row XOR key (u16 units)
  const float SCL = 0.0450842200277855f;  // (1/32) * log2(e)

  auto stageK = [&](int kv0, int bb) {
#pragma unroll
    for (int r = 0; r < 2; ++r) {
      const int dl = (r * 256 + t) * 16;
      const int row = dl >> 7;
      const int srcb = (dl & 127) ^ ((row & 7) << 4);
      gl_lds16(Kg + (size_t)(kv0 + row) * 3072 + (srcb >> 1),
               (char*)Ks[bb] + r * 4096 + w * 1024);
    }
  };
  auto stageV = [&](int kv0, int bb) {
#pragma unroll
    for (int r = 0; r < 2; ++r) {
      const int dl = (r * 256 + t) * 16;
      const int dh = dl >> 7;
      const int srcb = (dl & 127) ^ ((dh & 7) << 4);
      gl_lds16(Vg + (size_t)dh * 2048 + kv0 + (srcb >> 1),
               (char*)Vs[bb] + r * 4096 + w * 1024);
    }
  };

  const int q0w = qt * 64 + w * 16;
  const u16* Qp = qkvb + base + (size_t)(q0w + lr) * 3072 + h * 64;
  const bf16x8 qf0 = *(const bf16x8*)(Qp + g * 8);
  const bf16x8 qf1 = *(const bf16x8*)(Qp + 32 + g * 8);
  f32x4 o[4] = {};
  float m1 = -1e30f, s1 = 0.f;  // m1 in SCALED (log2) domain

  stageK(t_begin * 64, 0);
  stageV(t_begin * 64, 0);
  __syncthreads();

  int ct = 0;
  for (int tt = t_begin; tt < t_end; ++tt) {
    const int kv0 = tt * 64;
    if (tt + 1 < t_end) {
      stageK(kv0 + 64, ct ^ 1);
      stageV(kv0 + 64, ct ^ 1);
    }

    const u16* Kbuf = Ks[ct];
    const u16* Vbuf = Vs[ct];
    // ---- QK^T swapped (RAW, no scale): s4[i][r] = S[kv0+i*16+g*4+r][q0w+lr] ----
    f32x4 s4[4];
#pragma unroll
    for (int i = 0; i < 4; ++i) {
      const int row = i * 16 + lr;
      const int sw = (row & 7) << 4;
      const bf16x8 k0 = *(const bf16x8*)(Kbuf + row * 64 + (((g * 16) ^ sw) >> 1));
      const bf16x8 k1 = *(const bf16x8*)(Kbuf + row * 64 + (((64 + g * 16) ^ sw) >> 1));
      f32x4 z = {0.f, 0.f, 0.f, 0.f};
      z = mfma16(k0, qf0, z);
      s4[i] = mfma16(k1, qf1, z);
    }
    if (kv0 + 64 > q0w) {  // causal: kv > q
#pragma unroll
      for (int i = 0; i < 4; ++i)
#pragma unroll
        for (int r = 0; r < 4; ++r)
          if (kv0 + i * 16 + g * 4 + r > q0w + lr) s4[i][r] = -1e30f;
    }
    // ---- softmax: raw-domain max tree, single scale; defer-max ----
    const f32x4 mm = fmax4(fmax4(s4[0], s4[1]), fmax4(s4[2], s4[3]));
    float mx = fmaxf(fmaxf(mm[0], mm[1]), fmaxf(mm[2], mm[3]));
    mx = fmaxf(mx, __shfl_xor(mx, 16));
    mx = fmaxf(mx, __shfl_xor(mx, 32));
    const float mxs = mx * SCL;
    if (!__all(mxs <= m1 + 8.f)) {
      const float mn = fmaxf(m1, mxs);
      const float sc = exp2f(m1 - mn);
      m1 = mn;
      s1 *= sc;
      float scr[4];
#pragma unroll
      for (int r = 0; r < 4; ++r) scr[r] = __shfl(sc, g * 4 + r);
#pragma unroll
      for (int n = 0; n < 4; ++n)
#pragma unroll
        for (int r = 0; r < 4; ++r) o[n][r] *= scr[r];
    }
    float ps = 0.f;
#pragma unroll
    for (int i = 0; i < 4; ++i) {
      u16x4 pk;
#pragma unroll
      for (int r = 0; r < 4; ++r) {
        const float p = exp2f(fmaf(s4[i][r], SCL, -m1));
        ps += p;
        pk[r] = f2bf(p);
      }
      *(u16x4*)(Pw + lr * 64 + ((i * 16 + g * 4) ^ pkey)) = pk;
    }
    s1 += ps;
    // ---- PV ----
#pragma unroll
    for (int s = 0; s < 2; ++s) {
      const bf16x8 pa = *(const bf16x8*)(Pw + lr * 64 + ((s * 32 + g * 8) ^ pkey));
#pragma unroll
      for (int n = 0; n < 4; ++n) {
        const int dh = n * 16 + lr;
        const bf16x8 vf = *(const bf16x8*)(
            Vbuf + dh * 64 + (((s * 64 + g * 16) ^ ((dh & 7) << 4)) >> 1));
        o[n] = mfma16(pa, vf, o[n]);
      }
    }
    __syncthreads();
    ct ^= 1;
  }

  // ---- cross-g denominator ----
  float den = s1;
  den += __shfl_xor(den, 16);
  den += __shfl_xor(den, 32);

  if (split) {
    // write unnormalized partials: po[pidx][64 rows][64 cols], pm[pidx][64 rows][2]
    const int pidx = (bh * 17 + (qt - 15)) * 2 + seg;
    float* pob = po + ((size_t)pidx * 64 + w * 16) * 64;
#pragma unroll
    for (int n = 0; n < 4; ++n)
#pragma unroll
      for (int r = 0; r < 4; ++r)
        pob[(g * 4 + r) * 64 + n * 16 + lr] = o[n][r];
    if (l < 16)
      *(float2*)(pm + ((size_t)pidx * 64 + w * 16 + l) * 2) = make_float2(m1, den);
  } else {
    const float iv = 1.f / den;
    float ivr[4];
#pragma unroll
    for (int r = 0; r < 4; ++r) ivr[r] = __shfl(iv, g * 4 + r);
#pragma unroll
    for (int n = 0; n < 4; ++n)
#pragma unroll
      for (int r = 0; r < 4; ++r) {
        const int row = q0w + g * 4 + r;
        const int col = h * 64 + n * 16 + lr;
        y[(size_t)(b * 2048 + row) * 1024 + col] = f2bf(o[n][r] * ivr[r]);
      }
  }
}

// ---- combine split-attention partials: one block per (bh, qt>=15) -------------------
__global__ __launch_bounds__(256) void attn_combine(const float* __restrict__ po,
                                                    const float* __restrict__ pm,
                                                    u16* __restrict__ y) {
  const int c = blockIdx.x;          // 0..543 = 32 bh x 17 qt
  const int bh = c & 31, qti = c >> 5;
  const int qt = 15 + qti;
  const int b = bh >> 4, h = bh & 15;
  const int t = threadIdx.x;
  const int row = t >> 2, c0 = (t & 3) * 16;
  const int pidx = (bh * 17 + qti) * 2;
  const float2 ms0 = *(const float2*)(pm + ((size_t)(pidx + 0) * 64 + row) * 2);
  const float2 ms1 = *(const float2*)(pm + ((size_t)(pidx + 1) * 64 + row) * 2);
  const float mm = fmaxf(ms0.x, ms1.x);
  const float w0 = exp2f(ms0.x - mm), w1 = exp2f(ms1.x - mm);
  const float inv = 1.f / (ms0.y * w0 + ms1.y * w1);
  const float* p0 = po + ((size_t)(pidx + 0) * 64 + row) * 64 + c0;
  const float* p1 = po + ((size_t)(pidx + 1) * 64 + row) * 64 + c0;
  u16* yp = y + (size_t)(b * 2048 + qt * 64 + row) * 1024 + h * 64 + c0;
#pragma unroll
  for (int jj = 0; jj < 4; ++jj) {
    const float4 a = ((const float4*)p0)[jj];
    const float4 bb = ((const float4*)p1)[jj];
    ushort4 ov;
    ov.x = f2bf((a.x * w0 + bb.x * w1) * inv);
    ov.y = f2bf((a.y * w0 + bb.y * w1) * inv);
    ov.z = f2bf((a.z * w0 + bb.z * w1) * inv);
    ov.w = f2bf((a.w * w0 + bb.w * w1) * inv);
    ((ushort4*)yp)[jj] = ov;
  }
}

// ------------------------------------------------------------------------------------
// ws layout (MB), peak 120:
//   0..24  qkvb | later projP (4 x 8MB, after attn) | later cprojP
//  24..32  h1 (dead after qkv)
//  32..49.4 po (attn partials; dead after combine) | 48..64 x1 (written by reduce_ln)
//  50..50.6 pm (attn partials)
//  64..72  yb (attn out) | h2 (reduce_ln out, after proj)
//  72..80  vT (dead before hf) | 72..104 hf
// 104..112 wattnT(6)+wprojT(2) -> later wcprojT(8)
// 112..120 wfcT
extern "C" void kernel_launch(void* const* d_in, const int* in_sizes, int n_in,
                              void* d_out, int out_size, void* d_ws, size_t ws_size,
                              hipStream_t stream) {
  const float* x      = (const float*)d_in[0];
  const float* ln1w   = (const float*)d_in[1];
  const float* wattn  = (const float*)d_in[2];
  const float* wproj  = (const float*)d_in[3];
  const float* ln2w   = (const float*)d_in[4];
  const float* wfc    = (const float*)d_in[5];
  const float* wcproj = (const float*)d_in[6];
  float* out = (float*)d_out;
  char* ws = (char*)d_ws;
  const size_t MB = 1024 * 1024;
  u16* qkvb    = (u16*)(ws + 0);
  u16* projP   = (u16*)(ws + 0);
  u16* cprojP  = (u16*)(ws + 0);
  u16* h1      = (u16*)(ws + 24 * MB);
  float* po    = (float*)(ws + 32 * MB);  // 17.4MB attn partial O
  float* x1    = (float*)(ws + 48 * MB);
  float* pm    = (float*)(ws + 50 * MB);  // 0.56MB attn partial m/s
  u16* yb      = (u16*)(ws + 64 * MB);
  u16* h2      = (u16*)(ws + 64 * MB);
  u16* vT      = (u16*)(ws + 72 * MB);
  u16* hf      = (u16*)(ws + 72 * MB);
  u16* wattnT  = (u16*)(ws + 104 * MB);
  u16* wprojT  = (u16*)(ws + 110 * MB);
  u16* wcprojT = (u16*)(ws + 104 * MB);
  u16* wfcT    = (u16*)(ws + 112 * MB);

  convT_all<<<2048, 256, 0, stream>>>(wattn, wattnT, wproj, wprojT, wfc, wfcT);

  ln_bf16<<<4096, 256, 0, stream>>>(x, ln1w, h1);
  gemm256<0><<<dim3(12, 16, 1), 512, 0, stream>>>(h1, wattnT, qkvb, 4096, 3072, 1024);
  vtrans<<<dim3(32, 32), 256, 0, stream>>>(qkvb, vT);
  attn_fwd<<<1568, 256, 0, stream>>>(qkvb, vT, yb, po, pm);
  attn_combine<<<544, 256, 0, stream>>>(po, pm, yb);
  gemm128<4><<<dim3(8, 32, 4), 256, 0, stream>>>(yb, wprojT, projP, 4096, 1024, 1024);
  convT<<<dim3(64, 16), 256, 0, stream>>>(wcproj, wcprojT, 4096, 1024);
  reduce_ln<<<4096, 256, 0, stream>>>(x, projP, 4, ln2w, x1, h2);
  gemm256<2><<<dim3(16, 16, 1), 512, 0, stream>>>(h2, wfcT, hf, 4096, 4096, 1024);
  gemm256<4><<<dim3(4, 16, 4), 512, 0, stream>>>(hf, wcprojT, cprojP, 4096, 1024, 4096);
  reduce_out<<<4096, 256, 0, stream>>>(x1, cprojP, 4, out);
}

// Round 18
// 232.288 us; speedup vs baseline: 1.0027x; 1.0027x over previous
//
#include <hip/hip_runtime.h>

typedef __attribute__((ext_vector_type(8))) __bf16 bf16x8;
typedef __attribute__((ext_vector_type(4))) float f32x4;
typedef __attribute__((ext_vector_type(8))) unsigned short u16x8;
typedef __attribute__((ext_vector_type(4))) unsigned short u16x4;
typedef unsigned short u16;

__device__ __forceinline__ u16 f2bf(float f) {
  return __builtin_bit_cast(u16, (__bf16)f);
}
__device__ __forceinline__ float bf2f(u16 u) {
  return __builtin_bit_cast(float, ((unsigned)u) << 16);
}

__device__ __forceinline__ f32x4 mfma16(bf16x8 a, bf16x8 b, f32x4 c) {
  return __builtin_amdgcn_mfma_f32_16x16x32_bf16(a, b, c, 0, 0, 0);
}

__device__ __forceinline__ void gl_lds16(const void* g, void* l) {
  __builtin_amdgcn_global_load_lds(
      (const __attribute__((address_space(1))) unsigned int*)g,
      (__attribute__((address_space(3))) unsigned int*)l, 16, 0, 0);
}

__device__ __forceinline__ f32x4 fmax4(f32x4 a, f32x4 b) {
  f32x4 r;
  r[0] = fmaxf(a[0], b[0]); r[1] = fmaxf(a[1], b[1]);
  r[2] = fmaxf(a[2], b[2]); r[3] = fmaxf(a[3], b[3]);
  return r;
}

// ---- batched transpose+convert: 3 weight jobs in one launch -------------------------
__global__ __launch_bounds__(256) void convT_all(const float* __restrict__ w0,
                                                 u16* __restrict__ o0,
                                                 const float* __restrict__ w1,
                                                 u16* __restrict__ o1,
                                                 const float* __restrict__ w2,
                                                 u16* __restrict__ o2) {
  __shared__ float tile[64][65];
  const int id = blockIdx.x;
  const float* in;
  u16* outT;
  int K, N, bx, by;
  if (id < 768) { in = w0; outT = o0; K = 1024; N = 3072; bx = id & 15; by = id >> 4; }
  else if (id < 1024) { const int j = id - 768; in = w1; outT = o1; K = 1024; N = 1024; bx = j & 15; by = j >> 4; }
  else { const int j = id - 1024; in = w2; outT = o2; K = 1024; N = 4096; bx = j & 15; by = j >> 4; }
  const int t = threadIdx.x;
  const int tk = bx * 64, tn = by * 64;
  const int lk = t >> 4, ln = (t & 15) * 4;
#pragma unroll
  for (int r = 0; r < 4; ++r) {
    const int k = lk + r * 16;
    const float4 v = *(const float4*)(in + (size_t)(tk + k) * N + tn + ln);
    tile[k][ln + 0] = v.x; tile[k][ln + 1] = v.y;
    tile[k][ln + 2] = v.z; tile[k][ln + 3] = v.w;
  }
  __syncthreads();
  const int sn = t >> 2, sk = (t & 3) * 4;
#pragma unroll
  for (int j = 0; j < 4; ++j) {
    const int k = sk + j * 16;
    ushort4 o;
    o.x = f2bf(tile[k + 0][sn]); o.y = f2bf(tile[k + 1][sn]);
    o.z = f2bf(tile[k + 2][sn]); o.w = f2bf(tile[k + 3][sn]);
    *(ushort4*)(outT + (size_t)(tn + sn) * K + tk + k) = o;
  }
}

// ---------------- single transpose+convert (wcproj, mid-pipeline) --------------------
__global__ __launch_bounds__(256) void convT(const float* __restrict__ in,
                                             u16* __restrict__ outT, int K, int N) {
  __shared__ float tile[64][65];
  const int t = threadIdx.x;
  const int tk = blockIdx.x * 64, tn = blockIdx.y * 64;
  const int lk = t >> 4, ln = (t & 15) * 4;
#pragma unroll
  for (int r = 0; r < 4; ++r) {
    const int k = lk + r * 16;
    const float4 v = *(const float4*)(in + (size_t)(tk + k) * N + tn + ln);
    tile[k][ln + 0] = v.x; tile[k][ln + 1] = v.y;
    tile[k][ln + 2] = v.z; tile[k][ln + 3] = v.w;
  }
  __syncthreads();
  const int sn = t >> 2, sk = (t & 3) * 4;
#pragma unroll
  for (int j = 0; j < 4; ++j) {
    const int k = sk + j * 16;
    ushort4 o;
    o.x = f2bf(tile[k + 0][sn]); o.y = f2bf(tile[k + 1][sn]);
    o.z = f2bf(tile[k + 2][sn]); o.w = f2bf(tile[k + 3][sn]);
    *(ushort4*)(outT + (size_t)(tn + sn) * K + tk + k) = o;
  }
}

// ---- V transpose (bf16): vT[bh][dh][t] = qkv[b*2048+t][2048 + h*64 + dh] ------------
__global__ __launch_bounds__(256) void vtrans(const u16* __restrict__ qkvb,
                                              u16* __restrict__ vT) {
  __shared__ u16 tile[64][72];
  const int t = threadIdx.x;
  const int tt0 = blockIdx.x * 64;
  const int bh = blockIdx.y;
  const int b = bh >> 4, h = bh & 15;
  const u16* src = qkvb + (size_t)(b * 2048 + tt0) * 3072 + 2048 + h * 64;
  {
    const int tl = t >> 2, d0 = (t & 3) * 16;
    const u16x8 a0 = *(const u16x8*)(src + (size_t)tl * 3072 + d0);
    const u16x8 a1 = *(const u16x8*)(src + (size_t)tl * 3072 + d0 + 8);
    *(u16x8*)(&tile[tl][d0]) = a0;
    *(u16x8*)(&tile[tl][d0 + 8]) = a1;
  }
  __syncthreads();
  {
    const int dh = t >> 2, t0 = (t & 3) * 16;
    u16x8 o0, o1;
#pragma unroll
    for (int jj = 0; jj < 8; ++jj) {
      o0[jj] = tile[t0 + jj][dh];
      o1[jj] = tile[t0 + 8 + jj][dh];
    }
    u16* dst = vT + ((size_t)bh * 64 + dh) * 2048 + tt0 + t0;
    *(u16x8*)dst = o0;
    *(u16x8*)(dst + 8) = o1;
  }
}

// ---------------- LayerNorm (C=1024 fixed), fp32 in -> bf16 out ----------------------
__global__ __launch_bounds__(256) void ln_bf16(const float* __restrict__ x,
                                               const float* __restrict__ wgt,
                                               u16* __restrict__ out) {
  const int row = blockIdx.x, t = threadIdx.x;
  const float4 v = ((const float4*)(x + (size_t)row * 1024))[t];
  float s = v.x + v.y + v.z + v.w;
  float q = v.x * v.x + v.y * v.y + v.z * v.z + v.w * v.w;
#pragma unroll
  for (int d = 32; d; d >>= 1) { s += __shfl_xor(s, d); q += __shfl_xor(q, d); }
  __shared__ float sb[8];
  const int wv = t >> 6;
  if ((t & 63) == 0) { sb[wv] = s; sb[4 + wv] = q; }
  __syncthreads();
  s = sb[0] + sb[1] + sb[2] + sb[3];
  q = sb[4] + sb[5] + sb[6] + sb[7];
  const float mu = s * (1.f / 1024.f);
  const float rstd = rsqrtf(q * (1.f / 1024.f) - mu * mu + 1e-5f);
  const float4 w4 = ((const float4*)wgt)[t];
  ushort4 o;
  o.x = f2bf((v.x - mu) * rstd * w4.x);
  o.y = f2bf((v.y - mu) * rstd * w4.y);
  o.z = f2bf((v.z - mu) * rstd * w4.z);
  o.w = f2bf((v.w - mu) * rstd * w4.w);
  *(ushort4*)(out + (size_t)row * 1024 + t * 4) = o;
}

// ---- reduce_ln: x1 = x + sum(bf16 partials); h2 = LN(x1)*w. one block per row -------
__global__ __launch_bounds__(256) void reduce_ln(const float* __restrict__ x,
                                                 const u16* __restrict__ p, int nseg,
                                                 const float* __restrict__ wgt,
                                                 float* __restrict__ x1,
                                                 u16* __restrict__ h2) {
  const int row = blockIdx.x, t = threadIdx.x;
  const size_t ro = (size_t)row * 1024 + t * 4;
  float4 v = *(const float4*)(x + ro);
  for (int sgm = 0; sgm < nseg; ++sgm) {
    const ushort4 u = *(const ushort4*)(p + (size_t)sgm * 4096 * 1024 + ro);
    v.x += bf2f(u.x); v.y += bf2f(u.y); v.z += bf2f(u.z); v.w += bf2f(u.w);
  }
  *(float4*)(x1 + ro) = v;
  float s = v.x + v.y + v.z + v.w;
  float q = v.x * v.x + v.y * v.y + v.z * v.z + v.w * v.w;
#pragma unroll
  for (int d = 32; d; d >>= 1) { s += __shfl_xor(s, d); q += __shfl_xor(q, d); }
  __shared__ float sb[8];
  const int wv = t >> 6;
  if ((t & 63) == 0) { sb[wv] = s; sb[4 + wv] = q; }
  __syncthreads();
  s = sb[0] + sb[1] + sb[2] + sb[3];
  q = sb[4] + sb[5] + sb[6] + sb[7];
  const float mu = s * (1.f / 1024.f);
  const float rstd = rsqrtf(q * (1.f / 1024.f) - mu * mu + 1e-5f);
  const float4 w4 = ((const float4*)wgt)[t];
  ushort4 o;
  o.x = f2bf((v.x - mu) * rstd * w4.x);
  o.y = f2bf((v.y - mu) * rstd * w4.y);
  o.z = f2bf((v.z - mu) * rstd * w4.z);
  o.w = f2bf((v.w - mu) * rstd * w4.w);
  *(ushort4*)(h2 + ro) = o;
}

// ---- reduce_out: out = x1 + sum(bf16 partials). one float4 per thread ---------------
__global__ __launch_bounds__(256) void reduce_out(const float* __restrict__ x1,
                                                  const u16* __restrict__ p, int nseg,
                                                  float* __restrict__ out) {
  const int i = blockIdx.x * blockDim.x + threadIdx.x;
  const size_t ro = (size_t)i * 4;
  float4 v = *(const float4*)(x1 + ro);
  for (int sgm = 0; sgm < nseg; ++sgm) {
    const ushort4 u = *(const ushort4*)(p + (size_t)sgm * 4096 * 1024 + ro);
    v.x += bf2f(u.x); v.y += bf2f(u.y); v.z += bf2f(u.z); v.w += bf2f(u.w);
  }
  *(float4*)(out + ro) = v;
}

// ---------------- 128x128 bf16 MFMA GEMM (proj, split-K partials) --------------------
template <int EPI>
__global__ __launch_bounds__(256) void gemm128(const u16* __restrict__ A,
                                               const u16* __restrict__ Bt,
                                               void* __restrict__ outp,
                                               int M, int N, int K) {
  __shared__ u16 As[2][4096];
  __shared__ u16 Bs[2][4096];
  const unsigned gx = gridDim.x, gy = gridDim.y, gxy = gx * gy;
  const unsigned nwg = gxy * gridDim.z;
  unsigned f = (blockIdx.z * gy + blockIdx.y) * gx + blockIdx.x;
  if ((nwg & 7u) == 0u) { const unsigned qq = nwg >> 3; f = (f & 7u) * qq + (f >> 3); }
  const int bx = f % gx, by = (f / gx) % gy, bz = f / gxy;

  const int t = threadIdx.x, w = t >> 6, l = t & 63;
  const int lr = l & 15, g = l >> 4;
  const int row0 = by * 128, col0 = bx * 128;
  const int segK = K / gridDim.z;
  const int k0 = bz * segK, kend = k0 + segK;
  const int wr = w >> 1, wc = w & 1;
  f32x4 acc[4][4] = {};

  const int sr = t >> 2;
  const int sk = (((t & 3) ^ (sr & 3)) << 3);
  const u16* Ag = A + (size_t)(row0 + sr) * K + sk;
  const u16* Bg = Bt + (size_t)(col0 + sr) * K + sk;
  const size_t rstride = (size_t)64 * K;

  auto stage = [&](int kt, int bb) {
    u16* AsW = As[bb] + w * 512;
    u16* BsW = Bs[bb] + w * 512;
    gl_lds16(Ag + kt, AsW);
    gl_lds16(Ag + kt + rstride, AsW + 2048);
    gl_lds16(Bg + kt, BsW);
    gl_lds16(Bg + kt + rstride, BsW + 2048);
  };

  const int gsw = (g ^ (lr & 3)) * 8;

  stage(k0, 0);
  __syncthreads();
  int cur = 0;
  for (int kt = k0; kt < kend; kt += 32) {
    if (kt + 32 < kend) stage(kt + 32, cur ^ 1);
    bf16x8 af[4], bfr[4];
#pragma unroll
    for (int m = 0; m < 4; ++m)
      af[m] = *(const bf16x8*)(As[cur] + (wr * 64 + m * 16 + lr) * 32 + gsw);
#pragma unroll
    for (int n = 0; n < 4; ++n)
      bfr[n] = *(const bf16x8*)(Bs[cur] + (wc * 64 + n * 16 + lr) * 32 + gsw);
#pragma unroll
    for (int m = 0; m < 4; ++m)
#pragma unroll
      for (int n = 0; n < 4; ++n) acc[m][n] = mfma16(af[m], bfr[n], acc[m][n]);
    __syncthreads();
    cur ^= 1;
  }

  const size_t segoff = (size_t)bz * M * N;
#pragma unroll
  for (int m = 0; m < 4; ++m)
#pragma unroll
    for (int n = 0; n < 4; ++n)
#pragma unroll
      for (int r = 0; r < 4; ++r) {
        const int row = row0 + wr * 64 + m * 16 + g * 4 + r;
        const int col = col0 + wc * 64 + n * 16 + lr;
        const size_t idx = (size_t)row * N + col;
        const float v = acc[m][n][r];
        if constexpr (EPI == 0) ((u16*)outp)[idx] = f2bf(v);
        else if constexpr (EPI == 2) ((u16*)outp)[idx] = f2bf(fmaxf(v, 0.f));
        else ((u16*)outp)[segoff + idx] = f2bf(v);
      }
}

// ---------------- 256x256 8-phase bf16 GEMM (qkv / fc / cproj) -----------------------
// R15 schedule + relaxed two-point waits (T4): sub3 waits only next tile's kh0
// (vmcnt(8), issued 6 phases prior); kh1 certified just-in-time at sub1 (vmcnt(8),
// 4-5 phases old) instead of a full tile early. Tail tiles use exact counts.
template <int EPI>
__global__ __launch_bounds__(512, 2) void gemm256(const u16* __restrict__ A,
                                                  const u16* __restrict__ Bt,
                                                  u16* __restrict__ outp,
                                                  int M, int N, int K) {
  __shared__ u16 S[2][32768];  // [buf][ A: kh0 0..8191, kh1 8192..16383 | B: +16384 ]
  const unsigned gx = gridDim.x, gy = gridDim.y, gxy = gx * gy;
  const unsigned nwg = gxy * gridDim.z;
  unsigned f = (blockIdx.z * gy + blockIdx.y) * gx + blockIdx.x;
  if ((nwg & 7u) == 0u) { const unsigned qq = nwg >> 3; f = (f & 7u) * qq + (f >> 3); }
  const int bx = f % gx, by = (f / gx) % gy, bz = f / gxy;
  const int t = threadIdx.x, w = t >> 6, l = t & 63;
  const int lr = l & 15, g = l >> 4;
  const int wr = w >> 2, wc = w & 3;
  const int row0 = by * 256, col0 = bx * 256;
  const int segK = K / gridDim.z;
  const int k0 = bz * segK;
  const int NT = segK >> 6;

  f32x4 acc[8][4] = {};

  const int jr0 = t >> 2;
  const int jr1 = jr0 + 128;
  const int jks = ((t & 3) ^ (jr0 & 3)) << 3;
  auto stage_half = [&](int ht, int idx) {
    const int buf = ht & 1;
    u16* db = &S[buf][(idx & 1) * 16384 + (idx >> 1) * 8192 + w * 512];
    const u16* gb = (idx & 1) ? Bt : A;
    const int rc0 = (idx & 1) ? col0 : row0;
    const int kb = k0 + ht * 64 + (idx >> 1) * 32;
    gl_lds16(gb + (size_t)(rc0 + jr0) * K + kb + jks, db);
    gl_lds16(gb + (size_t)(rc0 + jr1) * K + kb + jks, db + 4096);
  };

  const int gsw = (g ^ (lr & 3)) * 8;

  stage_half(0, 0); stage_half(0, 1); stage_half(0, 2); stage_half(0, 3);
  stage_half(1, 0); stage_half(1, 1);
  asm volatile("s_waitcnt vmcnt(8)" ::: "memory");  // tile0 kh0 landed
  __builtin_amdgcn_s_barrier();

  for (int T = 0; T < NT; ++T) {
    const int cur = T & 1;
    const u16* Ab = &S[cur][0];
    const u16* Bb = &S[cur][16384];
    bf16x8 bfr[4];
#pragma unroll
    for (int sub = 0; sub < 4; ++sub) {
      const int mq = sub & 1, ks = sub >> 1;
      if (mq == 0) {
#pragma unroll
        for (int n = 0; n < 4; ++n)
          bfr[n] = *(const bf16x8*)(Bb + ks * 8192 + (wc * 64 + n * 16 + lr) * 32 + gsw);
      }
      bf16x8 af[4];
#pragma unroll
      for (int m = 0; m < 4; ++m)
        af[m] = *(const bf16x8*)(Ab + ks * 8192 +
                                 (wr * 128 + mq * 64 + m * 16 + lr) * 32 + gsw);
      if (sub < 2) { if (T + 1 < NT) stage_half(T + 1, 2 + sub); }
      else         { if (T + 2 < NT) stage_half(T + 2, sub - 2); }
      __builtin_amdgcn_s_barrier();
      __builtin_amdgcn_s_setprio(1);
#pragma unroll
      for (int m = 0; m < 4; ++m)
#pragma unroll
        for (int n = 0; n < 4; ++n)
          acc[mq * 4 + m][n] = mfma16(af[m], bfr[n], acc[mq * 4 + m][n]);
      __builtin_amdgcn_s_setprio(0);
      if (sub == 1) {  // certify THIS tile's kh1 before sub2/3 read it
        if (T + 1 < NT) asm volatile("s_waitcnt vmcnt(8)" ::: "memory");
        else            asm volatile("s_waitcnt vmcnt(0)" ::: "memory");
      } else if (sub == 3 && T + 1 < NT) {  // certify next tile's kh0
        if (T + 2 < NT) asm volatile("s_waitcnt vmcnt(8)" ::: "memory");
        else            asm volatile("s_waitcnt vmcnt(4)" ::: "memory");
      }
      __builtin_amdgcn_s_barrier();
    }
  }

  const size_t segoff = (size_t)bz * M * N;
#pragma unroll
  for (int m = 0; m < 8; ++m)
#pragma unroll
    for (int n = 0; n < 4; ++n)
#pragma unroll
      for (int r = 0; r < 4; ++r) {
        const int row = row0 + wr * 128 + m * 16 + g * 4 + r;
        const int col = col0 + wc * 64 + n * 16 + lr;
        const size_t idx = (size_t)row * N + col;
        const float v = acc[m][n][r];
        if constexpr (EPI == 0) outp[idx] = f2bf(v);
        else if constexpr (EPI == 2) outp[idx] = f2bf(fmaxf(v, 0.f));
        else outp[segoff + idx] = f2bf(v);
      }
}

// ---------------- causal flash attention, bf16 MFMA (R16-verified, reverted) ---------
__global__ __launch_bounds__(256) void attn_fwd(const u16* __restrict__ qkvb,
                                                const u16* __restrict__ vT,
                                                u16* __restrict__ y) {
  __shared__ u16 Ks[2][4096];     // 2 x 8KB, swizzled rows [kv][k]
  __shared__ u16 Vs[2][4096];     // 2 x 8KB, swizzled rows [dh][kv]
  __shared__ u16 Pb[4][16 * 64];  // per-wave P: [q 0..15][kv 0..63], XOR-swizzled
  const int t = threadIdx.x, w = t >> 6, l = t & 63;
  const int lr = l & 15, g = l >> 4;
  const unsigned f = blockIdx.y * gridDim.x + blockIdx.x;
  const int xcd = f & 7, j = f >> 3;
  const int bh = xcd + 8 * (j & 3);   // all q-tiles of one bh on one XCD
  const int qt = 31 - (j >> 2);       // descending qt: long blocks dispatch first
  const int b = bh >> 4, h = bh & 15;
  const size_t base = (size_t)b * 2048 * 3072;
  const u16* Kg = qkvb + base + 1024 + h * 64;
  const u16* Vg = vT + (size_t)bh * 64 * 2048;  // [dh][t]
  u16* Pw = &Pb[w][0];
  const int pkey = (lr & 7) << 3;         // P-row XOR key (u16 units)
  const float SCL = 0.0450842200277855f;  // (1/32) * log2(e)

  auto stageK = [&](int kv0, int bb) {
#pragma unroll
    for (int r = 0; r < 2; ++r) {
      const int dl = (r * 256 + t) * 16;
      const int row = dl >> 7;
      const int srcb = (dl & 127) ^ ((row & 7) << 4);
      gl_lds16(Kg + (size_t)(kv0 + row) * 3072 + (srcb >> 1),
               (char*)Ks[bb] + r * 4096 + w * 1024);
    }
  };
  auto stageV = [&](int kv0, int bb) {
#pragma unroll
    for (int r = 0; r < 2; ++r) {
      const int dl = (r * 256 + t) * 16;
      const int dh = dl >> 7;
      const int srcb = (dl & 127) ^ ((dh & 7) << 4);
      gl_lds16(Vg + (size_t)dh * 2048 + kv0 + (srcb >> 1),
               (char*)Vs[bb] + r * 4096 + w * 1024);
    }
  };

  const int q0w = qt * 64 + w * 16, nt = qt + 1;
  const u16* Qp = qkvb + base + (size_t)(q0w + lr) * 3072 + h * 64;
  const bf16x8 qf0 = *(const bf16x8*)(Qp + g * 8);
  const bf16x8 qf1 = *(const bf16x8*)(Qp + 32 + g * 8);
  f32x4 o[4] = {};
  float m1 = -1e30f, s1 = 0.f;  // m1 in SCALED (log2) domain

  stageK(0, 0);
  stageV(0, 0);
  __syncthreads();

  int ct = 0;
  for (int tt = 0; tt < nt; ++tt) {
    const int kv0 = tt * 64;
    if (tt + 1 < nt) {
      stageK(kv0 + 64, ct ^ 1);
      stageV(kv0 + 64, ct ^ 1);
    }

    const u16* Kbuf = Ks[ct];
    const u16* Vbuf = Vs[ct];
    // ---- QK^T swapped (RAW, no scale): s4[i][r] = S[kv0+i*16+g*4+r][q0w+lr] ----
    f32x4 s4[4];
#pragma unroll
    for (int i = 0; i < 4; ++i) {
      const int row = i * 16 + lr;
      const int sw = (row & 7) << 4;
      const bf16x8 k0 = *(const bf16x8*)(Kbuf + row * 64 + (((g * 16) ^ sw) >> 1));
      const bf16x8 k1 = *(const bf16x8*)(Kbuf + row * 64 + (((64 + g * 16) ^ sw) >> 1));
      f32x4 z = {0.f, 0.f, 0.f, 0.f};
      z = mfma16(k0, qf0, z);
      s4[i] = mfma16(k1, qf1, z);
    }
    if (kv0 + 64 > q0w) {  // causal: kv > q
#pragma unroll
      for (int i = 0; i < 4; ++i)
#pragma unroll
        for (int r = 0; r < 4; ++r)
          if (kv0 + i * 16 + g * 4 + r > q0w + lr) s4[i][r] = -1e30f;
    }
    // ---- softmax: raw-domain max tree, single scale; defer-max ----
    const f32x4 mm = fmax4(fmax4(s4[0], s4[1]), fmax4(s4[2], s4[3]));
    float mx = fmaxf(fmaxf(mm[0], mm[1]), fmaxf(mm[2], mm[3]));
    mx = fmaxf(mx, __shfl_xor(mx, 16));
    mx = fmaxf(mx, __shfl_xor(mx, 32));
    const float mxs = mx * SCL;
    if (!__all(mxs <= m1 + 8.f)) {
      const float mn = fmaxf(m1, mxs);
      const float sc = exp2f(m1 - mn);
      m1 = mn;
      s1 *= sc;
      float scr[4];
#pragma unroll
      for (int r = 0; r < 4; ++r) scr[r] = __shfl(sc, g * 4 + r);
#pragma unroll
      for (int n = 0; n < 4; ++n)
#pragma unroll
        for (int r = 0; r < 4; ++r) o[n][r] *= scr[r];
    }
    float ps = 0.f;
#pragma unroll
    for (int i = 0; i < 4; ++i) {
      u16x4 pk;
#pragma unroll
      for (int r = 0; r < 4; ++r) {
        const float p = exp2f(fmaf(s4[i][r], SCL, -m1));
        ps += p;
        pk[r] = f2bf(p);
      }
      *(u16x4*)(Pw + lr * 64 + ((i * 16 + g * 4) ^ pkey)) = pk;
    }
    s1 += ps;
    // ---- PV ----
#pragma unroll
    for (int s = 0; s < 2; ++s) {
      const bf16x8 pa = *(const bf16x8*)(Pw + lr * 64 + ((s * 32 + g * 8) ^ pkey));
#pragma unroll
      for (int n = 0; n < 4; ++n) {
        const int dh = n * 16 + lr;
        const bf16x8 vf = *(const bf16x8*)(
            Vbuf + dh * 64 + (((s * 64 + g * 16) ^ ((dh & 7) << 4)) >> 1));
        o[n] = mfma16(pa, vf, o[n]);
      }
    }
    __syncthreads();
    ct ^= 1;
  }

  // ---- epilogue ----
  float den = s1;
  den += __shfl_xor(den, 16);
  den += __shfl_xor(den, 32);
  const float iv = 1.f / den;
  float ivr[4];
#pragma unroll
  for (int r = 0; r < 4; ++r) ivr[r] = __shfl(iv, g * 4 + r);
#pragma unroll
  for (int n = 0; n < 4; ++n)
#pragma unroll
    for (int r = 0; r < 4; ++r) {
      const int row = q0w + g * 4 + r;
      const int col = h * 64 + n * 16 + lr;
      y[(size_t)(b * 2048 + row) * 1024 + col] = f2bf(o[n][r] * ivr[r]);
    }
}

// ------------------------------------------------------------------------------------
// ws layout (MB), peak 120:
//   0..24  qkvb | later projP (4 x 8MB, after attn) | later cprojP
//  24..32  h1 (dead after qkv)
//  48..64  x1 (f32)
//  64..72  yb (attn out) | h2 (reduce_ln out, after proj)
//  72..80  vT (dead before hf) | 72..104 hf
// 104..112 wattnT(6)+wprojT(2) -> later wcprojT(8)
// 112..120 wfcT
extern "C" void kernel_launch(void* const* d_in, const int* in_sizes, int n_in,
                              void* d_out, int out_size, void* d_ws, size_t ws_size,
                              hipStream_t stream) {
  const float* x      = (const float*)d_in[0];
  const float* ln1w   = (const float*)d_in[1];
  const float* wattn  = (const float*)d_in[2];
  const float* wproj  = (const float*)d_in[3];
  const float* ln2w   = (const float*)d_in[4];
  const float* wfc    = (const float*)d_in[5];
  const float* wcproj = (const float*)d_in[6];
  float* out = (float*)d_out;
  char* ws = (char*)d_ws;
  const size_t MB = 1024 * 1024;
  u16* qkvb    = (u16*)(ws + 0);
  u16* projP   = (u16*)(ws + 0);
  u16* cprojP  = (u16*)(ws + 0);
  u16* h1      = (u16*)(ws + 24 * MB);
  float* x1    = (float*)(ws + 48 * MB);
  u16* yb      = (u16*)(ws + 64 * MB);
  u16* h2      = (u16*)(ws + 64 * MB);
  u16* vT      = (u16*)(ws + 72 * MB);
  u16* hf      = (u16*)(ws + 72 * MB);
  u16* wattnT  = (u16*)(ws + 104 * MB);
  u16* wprojT  = (u16*)(ws + 110 * MB);
  u16* wcprojT = (u16*)(ws + 104 * MB);
  u16* wfcT    = (u16*)(ws + 112 * MB);

  convT_all<<<2048, 256, 0, stream>>>(wattn, wattnT, wproj, wprojT, wfc, wfcT);

  ln_bf16<<<4096, 256, 0, stream>>>(x, ln1w, h1);
  gemm256<0><<<dim3(12, 16, 1), 512, 0, stream>>>(h1, wattnT, qkvb, 4096, 3072, 1024);
  vtrans<<<dim3(32, 32), 256, 0, stream>>>(qkvb, vT);
  attn_fwd<<<dim3(32, 32), 256, 0, stream>>>(qkvb, vT, yb);
  gemm128<4><<<dim3(8, 32, 4), 256, 0, stream>>>(yb, wprojT, projP, 4096, 1024, 1024);
  convT<<<dim3(64, 16), 256, 0, stream>>>(wcproj, wcprojT, 4096, 1024);
  reduce_ln<<<4096, 256, 0, stream>>>(x, projP, 4, ln2w, x1, h2);
  gemm256<2><<<dim3(16, 16, 1), 512, 0, stream>>>(h2, wfcT, hf, 4096, 4096, 1024);
  gemm256<4><<<dim3(4, 16, 4), 512, 0, stream>>>(hf, wcprojT, cprojP, 4096, 1024, 4096);
  reduce_out<<<4096, 256, 0, stream>>>(x1, cprojP, 4, out);
}

// Round 19
// 227.646 us; speedup vs baseline: 1.0231x; 1.0204x over previous
//
#include <hip/hip_runtime.h>

typedef __attribute__((ext_vector_type(8))) __bf16 bf16x8;
typedef __attribute__((ext_vector_type(4))) float f32x4;
typedef __attribute__((ext_vector_type(8))) unsigned short u16x8;
typedef __attribute__((ext_vector_type(4))) unsigned short u16x4;
typedef unsigned short u16;

__device__ __forceinline__ u16 f2bf(float f) {
  return __builtin_bit_cast(u16, (__bf16)f);
}
__device__ __forceinline__ float bf2f(u16 u) {
  return __builtin_bit_cast(float, ((unsigned)u) << 16);
}

__device__ __forceinline__ f32x4 mfma16(bf16x8 a, bf16x8 b, f32x4 c) {
  return __builtin_amdgcn_mfma_f32_16x16x32_bf16(a, b, c, 0, 0, 0);
}

__device__ __forceinline__ void gl_lds16(const void* g, void* l) {
  __builtin_amdgcn_global_load_lds(
      (const __attribute__((address_space(1))) unsigned int*)g,
      (__attribute__((address_space(3))) unsigned int*)l, 16, 0, 0);
}

__device__ __forceinline__ f32x4 fmax4(f32x4 a, f32x4 b) {
  f32x4 r;
  r[0] = fmaxf(a[0], b[0]); r[1] = fmaxf(a[1], b[1]);
  r[2] = fmaxf(a[2], b[2]); r[3] = fmaxf(a[3], b[3]);
  return r;
}

// ---- batched transpose+convert: ALL 4 weight jobs in one launch ---------------------
// [0,768) wattn 1024x3072 ; [768,1024) wproj 1024x1024 ;
// [1024,2048) wfc 1024x4096 ; [2048,3072) wcproj 4096x1024
__global__ __launch_bounds__(256) void convT_all(const float* __restrict__ w0,
                                                 u16* __restrict__ o0,
                                                 const float* __restrict__ w1,
                                                 u16* __restrict__ o1,
                                                 const float* __restrict__ w2,
                                                 u16* __restrict__ o2,
                                                 const float* __restrict__ w3,
                                                 u16* __restrict__ o3) {
  __shared__ float tile[64][65];
  const int id = blockIdx.x;
  const float* in;
  u16* outT;
  int K, N, bx, by;
  if (id < 768) { in = w0; outT = o0; K = 1024; N = 3072; bx = id & 15; by = id >> 4; }
  else if (id < 1024) { const int j = id - 768; in = w1; outT = o1; K = 1024; N = 1024; bx = j & 15; by = j >> 4; }
  else if (id < 2048) { const int j = id - 1024; in = w2; outT = o2; K = 1024; N = 4096; bx = j & 15; by = j >> 4; }
  else { const int j = id - 2048; in = w3; outT = o3; K = 4096; N = 1024; bx = j & 63; by = j >> 6; }
  const int t = threadIdx.x;
  const int tk = bx * 64, tn = by * 64;
  const int lk = t >> 4, ln = (t & 15) * 4;
#pragma unroll
  for (int r = 0; r < 4; ++r) {
    const int k = lk + r * 16;
    const float4 v = *(const float4*)(in + (size_t)(tk + k) * N + tn + ln);
    tile[k][ln + 0] = v.x; tile[k][ln + 1] = v.y;
    tile[k][ln + 2] = v.z; tile[k][ln + 3] = v.w;
  }
  __syncthreads();
  const int sn = t >> 2, sk = (t & 3) * 4;
#pragma unroll
  for (int j = 0; j < 4; ++j) {
    const int k = sk + j * 16;
    ushort4 o;
    o.x = f2bf(tile[k + 0][sn]); o.y = f2bf(tile[k + 1][sn]);
    o.z = f2bf(tile[k + 2][sn]); o.w = f2bf(tile[k + 3][sn]);
    *(ushort4*)(outT + (size_t)(tn + sn) * K + tk + k) = o;
  }
}

// ---- V transpose (bf16): vT[bh][dh][t] = qkv[b*2048+t][2048 + h*64 + dh] ------------
__global__ __launch_bounds__(256) void vtrans(const u16* __restrict__ qkvb,
                                              u16* __restrict__ vT) {
  __shared__ u16 tile[64][72];
  const int t = threadIdx.x;
  const int tt0 = blockIdx.x * 64;
  const int bh = blockIdx.y;
  const int b = bh >> 4, h = bh & 15;
  const u16* src = qkvb + (size_t)(b * 2048 + tt0) * 3072 + 2048 + h * 64;
  {
    const int tl = t >> 2, d0 = (t & 3) * 16;
    const u16x8 a0 = *(const u16x8*)(src + (size_t)tl * 3072 + d0);
    const u16x8 a1 = *(const u16x8*)(src + (size_t)tl * 3072 + d0 + 8);
    *(u16x8*)(&tile[tl][d0]) = a0;
    *(u16x8*)(&tile[tl][d0 + 8]) = a1;
  }
  __syncthreads();
  {
    const int dh = t >> 2, t0 = (t & 3) * 16;
    u16x8 o0, o1;
#pragma unroll
    for (int jj = 0; jj < 8; ++jj) {
      o0[jj] = tile[t0 + jj][dh];
      o1[jj] = tile[t0 + 8 + jj][dh];
    }
    u16* dst = vT + ((size_t)bh * 64 + dh) * 2048 + tt0 + t0;
    *(u16x8*)dst = o0;
    *(u16x8*)(dst + 8) = o1;
  }
}

// ---------------- LayerNorm (C=1024 fixed), fp32 in -> bf16 out ----------------------
__global__ __launch_bounds__(256) void ln_bf16(const float* __restrict__ x,
                                               const float* __restrict__ wgt,
                                               u16* __restrict__ out) {
  const int row = blockIdx.x, t = threadIdx.x;
  const float4 v = ((const float4*)(x + (size_t)row * 1024))[t];
  float s = v.x + v.y + v.z + v.w;
  float q = v.x * v.x + v.y * v.y + v.z * v.z + v.w * v.w;
#pragma unroll
  for (int d = 32; d; d >>= 1) { s += __shfl_xor(s, d); q += __shfl_xor(q, d); }
  __shared__ float sb[8];
  const int wv = t >> 6;
  if ((t & 63) == 0) { sb[wv] = s; sb[4 + wv] = q; }
  __syncthreads();
  s = sb[0] + sb[1] + sb[2] + sb[3];
  q = sb[4] + sb[5] + sb[6] + sb[7];
  const float mu = s * (1.f / 1024.f);
  const float rstd = rsqrtf(q * (1.f / 1024.f) - mu * mu + 1e-5f);
  const float4 w4 = ((const float4*)wgt)[t];
  ushort4 o;
  o.x = f2bf((v.x - mu) * rstd * w4.x);
  o.y = f2bf((v.y - mu) * rstd * w4.y);
  o.z = f2bf((v.z - mu) * rstd * w4.z);
  o.w = f2bf((v.w - mu) * rstd * w4.w);
  *(ushort4*)(out + (size_t)row * 1024 + t * 4) = o;
}

// ---- reduce_ln: x1 = x + sum(bf16 partials); h2 = LN(x1)*w. one block per row -------
__global__ __launch_bounds__(256) void reduce_ln(const float* __restrict__ x,
                                                 const u16* __restrict__ p, int nseg,
                                                 const float* __restrict__ wgt,
                                                 float* __restrict__ x1,
                                                 u16* __restrict__ h2) {
  const int row = blockIdx.x, t = threadIdx.x;
  const size_t ro = (size_t)row * 1024 + t * 4;
  float4 v = *(const float4*)(x + ro);
  for (int sgm = 0; sgm < nseg; ++sgm) {
    const ushort4 u = *(const ushort4*)(p + (size_t)sgm * 4096 * 1024 + ro);
    v.x += bf2f(u.x); v.y += bf2f(u.y); v.z += bf2f(u.z); v.w += bf2f(u.w);
  }
  *(float4*)(x1 + ro) = v;
  float s = v.x + v.y + v.z + v.w;
  float q = v.x * v.x + v.y * v.y + v.z * v.z + v.w * v.w;
#pragma unroll
  for (int d = 32; d; d >>= 1) { s += __shfl_xor(s, d); q += __shfl_xor(q, d); }
  __shared__ float sb[8];
  const int wv = t >> 6;
  if ((t & 63) == 0) { sb[wv] = s; sb[4 + wv] = q; }
  __syncthreads();
  s = sb[0] + sb[1] + sb[2] + sb[3];
  q = sb[4] + sb[5] + sb[6] + sb[7];
  const float mu = s * (1.f / 1024.f);
  const float rstd = rsqrtf(q * (1.f / 1024.f) - mu * mu + 1e-5f);
  const float4 w4 = ((const float4*)wgt)[t];
  ushort4 o;
  o.x = f2bf((v.x - mu) * rstd * w4.x);
  o.y = f2bf((v.y - mu) * rstd * w4.y);
  o.z = f2bf((v.z - mu) * rstd * w4.z);
  o.w = f2bf((v.w - mu) * rstd * w4.w);
  *(ushort4*)(h2 + ro) = o;
}

// ---- reduce_out: out = x1 + sum(bf16 partials). one float4 per thread ---------------
__global__ __launch_bounds__(256) void reduce_out(const float* __restrict__ x1,
                                                  const u16* __restrict__ p, int nseg,
                                                  float* __restrict__ out) {
  const int i = blockIdx.x * blockDim.x + threadIdx.x;
  const size_t ro = (size_t)i * 4;
  float4 v = *(const float4*)(x1 + ro);
  for (int sgm = 0; sgm < nseg; ++sgm) {
    const ushort4 u = *(const ushort4*)(p + (size_t)sgm * 4096 * 1024 + ro);
    v.x += bf2f(u.x); v.y += bf2f(u.y); v.z += bf2f(u.z); v.w += bf2f(u.w);
  }
  *(float4*)(out + ro) = v;
}

// ---------------- 128x128 bf16 MFMA GEMM (proj, split-K partials) --------------------
template <int EPI>
__global__ __launch_bounds__(256) void gemm128(const u16* __restrict__ A,
                                               const u16* __restrict__ Bt,
                                               void* __restrict__ outp,
                                               int M, int N, int K) {
  __shared__ u16 As[2][4096];
  __shared__ u16 Bs[2][4096];
  const unsigned gx = gridDim.x, gy = gridDim.y, gxy = gx * gy;
  const unsigned nwg = gxy * gridDim.z;
  unsigned f = (blockIdx.z * gy + blockIdx.y) * gx + blockIdx.x;
  if ((nwg & 7u) == 0u) { const unsigned qq = nwg >> 3; f = (f & 7u) * qq + (f >> 3); }
  const int bx = f % gx, by = (f / gx) % gy, bz = f / gxy;

  const int t = threadIdx.x, w = t >> 6, l = t & 63;
  const int lr = l & 15, g = l >> 4;
  const int row0 = by * 128, col0 = bx * 128;
  const int segK = K / gridDim.z;
  const int k0 = bz * segK, kend = k0 + segK;
  const int wr = w >> 1, wc = w & 1;
  f32x4 acc[4][4] = {};

  const int sr = t >> 2;
  const int sk = (((t & 3) ^ (sr & 3)) << 3);
  const u16* Ag = A + (size_t)(row0 + sr) * K + sk;
  const u16* Bg = Bt + (size_t)(col0 + sr) * K + sk;
  const size_t rstride = (size_t)64 * K;

  auto stage = [&](int kt, int bb) {
    u16* AsW = As[bb] + w * 512;
    u16* BsW = Bs[bb] + w * 512;
    gl_lds16(Ag + kt, AsW);
    gl_lds16(Ag + kt + rstride, AsW + 2048);
    gl_lds16(Bg + kt, BsW);
    gl_lds16(Bg + kt + rstride, BsW + 2048);
  };

  const int gsw = (g ^ (lr & 3)) * 8;

  stage(k0, 0);
  __syncthreads();
  int cur = 0;
  for (int kt = k0; kt < kend; kt += 32) {
    if (kt + 32 < kend) stage(kt + 32, cur ^ 1);
    bf16x8 af[4], bfr[4];
#pragma unroll
    for (int m = 0; m < 4; ++m)
      af[m] = *(const bf16x8*)(As[cur] + (wr * 64 + m * 16 + lr) * 32 + gsw);
#pragma unroll
    for (int n = 0; n < 4; ++n)
      bfr[n] = *(const bf16x8*)(Bs[cur] + (wc * 64 + n * 16 + lr) * 32 + gsw);
#pragma unroll
    for (int m = 0; m < 4; ++m)
#pragma unroll
      for (int n = 0; n < 4; ++n) acc[m][n] = mfma16(af[m], bfr[n], acc[m][n]);
    __syncthreads();
    cur ^= 1;
  }

  const size_t segoff = (size_t)bz * M * N;
#pragma unroll
  for (int m = 0; m < 4; ++m)
#pragma unroll
    for (int n = 0; n < 4; ++n)
#pragma unroll
      for (int r = 0; r < 4; ++r) {
        const int row = row0 + wr * 64 + m * 16 + g * 4 + r;
        const int col = col0 + wc * 64 + n * 16 + lr;
        const size_t idx = (size_t)row * N + col;
        const float v = acc[m][n][r];
        if constexpr (EPI == 0) ((u16*)outp)[idx] = f2bf(v);
        else if constexpr (EPI == 2) ((u16*)outp)[idx] = f2bf(fmaxf(v, 0.f));
        else ((u16*)outp)[segoff + idx] = f2bf(v);
      }
}

// ---------------- 256x256 8-phase bf16 GEMM (qkv / fc / cproj) — R15 discipline ------
template <int EPI>
__global__ __launch_bounds__(512, 2) void gemm256(const u16* __restrict__ A,
                                                  const u16* __restrict__ Bt,
                                                  u16* __restrict__ outp,
                                                  int M, int N, int K) {
  __shared__ u16 S[2][32768];  // [buf][ A: kh0 0..8191, kh1 8192..16383 | B: +16384 ]
  const unsigned gx = gridDim.x, gy = gridDim.y, gxy = gx * gy;
  const unsigned nwg = gxy * gridDim.z;
  unsigned f = (blockIdx.z * gy + blockIdx.y) * gx + blockIdx.x;
  if ((nwg & 7u) == 0u) { const unsigned qq = nwg >> 3; f = (f & 7u) * qq + (f >> 3); }
  const int bx = f % gx, by = (f / gx) % gy, bz = f / gxy;
  const int t = threadIdx.x, w = t >> 6, l = t & 63;
  const int lr = l & 15, g = l >> 4;
  const int wr = w >> 2, wc = w & 3;
  const int row0 = by * 256, col0 = bx * 256;
  const int segK = K / gridDim.z;
  const int k0 = bz * segK;
  const int NT = segK >> 6;

  f32x4 acc[8][4] = {};

  const int jr0 = t >> 2;
  const int jr1 = jr0 + 128;
  const int jks = ((t & 3) ^ (jr0 & 3)) << 3;
  auto stage_half = [&](int ht, int idx) {
    const int buf = ht & 1;
    u16* db = &S[buf][(idx & 1) * 16384 + (idx >> 1) * 8192 + w * 512];
    const u16* gb = (idx & 1) ? Bt : A;
    const int rc0 = (idx & 1) ? col0 : row0;
    const int kb = k0 + ht * 64 + (idx >> 1) * 32;
    gl_lds16(gb + (size_t)(rc0 + jr0) * K + kb + jks, db);
    gl_lds16(gb + (size_t)(rc0 + jr1) * K + kb + jks, db + 4096);
  };

  const int gsw = (g ^ (lr & 3)) * 8;

  stage_half(0, 0); stage_half(0, 1); stage_half(0, 2); stage_half(0, 3);
  stage_half(1, 0); stage_half(1, 1);
  asm volatile("s_waitcnt vmcnt(4)" ::: "memory");  // tile0 landed; tile1-kh0 in flight
  __builtin_amdgcn_s_barrier();

  for (int T = 0; T < NT; ++T) {
    const int cur = T & 1;
    const u16* Ab = &S[cur][0];
    const u16* Bb = &S[cur][16384];
    bf16x8 bfr[4];
#pragma unroll
    for (int sub = 0; sub < 4; ++sub) {
      const int mq = sub & 1, ks = sub >> 1;
      if (mq == 0) {
#pragma unroll
        for (int n = 0; n < 4; ++n)
          bfr[n] = *(const bf16x8*)(Bb + ks * 8192 + (wc * 64 + n * 16 + lr) * 32 + gsw);
      }
      bf16x8 af[4];
#pragma unroll
      for (int m = 0; m < 4; ++m)
        af[m] = *(const bf16x8*)(Ab + ks * 8192 +
                                 (wr * 128 + mq * 64 + m * 16 + lr) * 32 + gsw);
      if (sub < 2) { if (T + 1 < NT) stage_half(T + 1, 2 + sub); }
      else         { if (T + 2 < NT) stage_half(T + 2, sub - 2); }
      __builtin_amdgcn_s_barrier();
      __builtin_amdgcn_s_setprio(1);
#pragma unroll
      for (int m = 0; m < 4; ++m)
#pragma unroll
        for (int n = 0; n < 4; ++n)
          acc[mq * 4 + m][n] = mfma16(af[m], bfr[n], acc[mq * 4 + m][n]);
      __builtin_amdgcn_s_setprio(0);
      if (sub == 3) asm volatile("s_waitcnt vmcnt(4)" ::: "memory");
      __builtin_amdgcn_s_barrier();
    }
  }

  const size_t segoff = (size_t)bz * M * N;
#pragma unroll
  for (int m = 0; m < 8; ++m)
#pragma unroll
    for (int n = 0; n < 4; ++n)
#pragma unroll
      for (int r = 0; r < 4; ++r) {
        const int row = row0 + wr * 128 + m * 16 + g * 4 + r;
        const int col = col0 + wc * 64 + n * 16 + lr;
        const size_t idx = (size_t)row * N + col;
        const float v = acc[m][n][r];
        if constexpr (EPI == 0) outp[idx] = f2bf(v);
        else if constexpr (EPI == 2) outp[idx] = f2bf(fmaxf(v, 0.f));
        else outp[segoff + idx] = f2bf(v);
      }
}

// ---------------- causal flash attention, bf16 MFMA (verified config) ----------------
__global__ __launch_bounds__(256) void attn_fwd(const u16* __restrict__ qkvb,
                                                const u16* __restrict__ vT,
                                                u16* __restrict__ y) {
  __shared__ u16 Ks[2][4096];     // 2 x 8KB, swizzled rows [kv][k]
  __shared__ u16 Vs[2][4096];     // 2 x 8KB, swizzled rows [dh][kv]
  __shared__ u16 Pb[4][16 * 64];  // per-wave P: [q 0..15][kv 0..63], XOR-swizzled
  const int t = threadIdx.x, w = t >> 6, l = t & 63;
  const int lr = l & 15, g = l >> 4;
  const unsigned f = blockIdx.y * gridDim.x + blockIdx.x;
  const int xcd = f & 7, j = f >> 3;
  const int bh = xcd + 8 * (j & 3);   // all q-tiles of one bh on one XCD
  const int qt = 31 - (j >> 2);       // descending qt: long blocks dispatch first
  const int b = bh >> 4, h = bh & 15;
  const size_t base = (size_t)b * 2048 * 3072;
  const u16* Kg = qkvb + base + 1024 + h * 64;
  const u16* Vg = vT + (size_t)bh * 64 * 2048;  // [dh][t]
  u16* Pw = &Pb[w][0];
  const int pkey = (lr & 7) << 3;         // P-row XOR key (u16 units)
  const float SCL = 0.0450842200277855f;  // (1/32) * log2(e)

  auto stageK = [&](int kv0, int bb) {
#pragma unroll
    for (int r = 0; r < 2; ++r) {
      const int dl = (r * 256 + t) * 16;
      const int row = dl >> 7;
      const int srcb = (dl & 127) ^ ((row & 7) << 4);
      gl_lds16(Kg + (size_t)(kv0 + row) * 3072 + (srcb >> 1),
               (char*)Ks[bb] + r * 4096 + w * 1024);
    }
  };
  auto stageV = [&](int kv0, int bb) {
#pragma unroll
    for (int r = 0; r < 2; ++r) {
      const int dl = (r * 256 + t) * 16;
      const int dh = dl >> 7;
      const int srcb = (dl & 127) ^ ((dh & 7) << 4);
      gl_lds16(Vg + (size_t)dh * 2048 + kv0 + (srcb >> 1),
               (char*)Vs[bb] + r * 4096 + w * 1024);
    }
  };

  const int q0w = qt * 64 + w * 16, nt = qt + 1;
  const u16* Qp = qkvb + base + (size_t)(q0w + lr) * 3072 + h * 64;
  const bf16x8 qf0 = *(const bf16x8*)(Qp + g * 8);
  const bf16x8 qf1 = *(const bf16x8*)(Qp + 32 + g * 8);
  f32x4 o[4] = {};
  float m1 = -1e30f, s1 = 0.f;  // m1 in SCALED (log2) domain

  stageK(0, 0);
  stageV(0, 0);
  __syncthreads();

  int ct = 0;
  for (int tt = 0; tt < nt; ++tt) {
    const int kv0 = tt * 64;
    if (tt + 1 < nt) {
      stageK(kv0 + 64, ct ^ 1);
      stageV(kv0 + 64, ct ^ 1);
    }

    const u16* Kbuf = Ks[ct];
    const u16* Vbuf = Vs[ct];
    // ---- QK^T swapped (RAW, no scale): s4[i][r] = S[kv0+i*16+g*4+r][q0w+lr] ----
    f32x4 s4[4];
#pragma unroll
    for (int i = 0; i < 4; ++i) {
      const int row = i * 16 + lr;
      const int sw = (row & 7) << 4;
      const bf16x8 k0 = *(const bf16x8*)(Kbuf + row * 64 + (((g * 16) ^ sw) >> 1));
      const bf16x8 k1 = *(const bf16x8*)(Kbuf + row * 64 + (((64 + g * 16) ^ sw) >> 1));
      f32x4 z = {0.f, 0.f, 0.f, 0.f};
      z = mfma16(k0, qf0, z);
      s4[i] = mfma16(k1, qf1, z);
    }
    if (kv0 + 64 > q0w) {  // causal: kv > q
#pragma unroll
      for (int i = 0; i < 4; ++i)
#pragma unroll
        for (int r = 0; r < 4; ++r)
          if (kv0 + i * 16 + g * 4 + r > q0w + lr) s4[i][r] = -1e30f;
    }
    // ---- softmax: raw-domain max tree, single scale; defer-max ----
    const f32x4 mm = fmax4(fmax4(s4[0], s4[1]), fmax4(s4[2], s4[3]));
    float mx = fmaxf(fmaxf(mm[0], mm[1]), fmaxf(mm[2], mm[3]));
    mx = fmaxf(mx, __shfl_xor(mx, 16));
    mx = fmaxf(mx, __shfl_xor(mx, 32));
    const float mxs = mx * SCL;
    if (!__all(mxs <= m1 + 8.f)) {
      const float mn = fmaxf(m1, mxs);
      const float sc = exp2f(m1 - mn);
      m1 = mn;
      s1 *= sc;
      float scr[4];
#pragma unroll
      for (int r = 0; r < 4; ++r) scr[r] = __shfl(sc, g * 4 + r);
#pragma unroll
      for (int n = 0; n < 4; ++n)
#pragma unroll
        for (int r = 0; r < 4; ++r) o[n][r] *= scr[r];
    }
    float ps = 0.f;
#pragma unroll
    for (int i = 0; i < 4; ++i) {
      u16x4 pk;
#pragma unroll
      for (int r = 0; r < 4; ++r) {
        const float p = exp2f(fmaf(s4[i][r], SCL, -m1));
        ps += p;
        pk[r] = f2bf(p);
      }
      *(u16x4*)(Pw + lr * 64 + ((i * 16 + g * 4) ^ pkey)) = pk;
    }
    s1 += ps;
    // ---- PV ----
#pragma unroll
    for (int s = 0; s < 2; ++s) {
      const bf16x8 pa = *(const bf16x8*)(Pw + lr * 64 + ((s * 32 + g * 8) ^ pkey));
#pragma unroll
      for (int n = 0; n < 4; ++n) {
        const int dh = n * 16 + lr;
        const bf16x8 vf = *(const bf16x8*)(
            Vbuf + dh * 64 + (((s * 64 + g * 16) ^ ((dh & 7) << 4)) >> 1));
        o[n] = mfma16(pa, vf, o[n]);
      }
    }
    __syncthreads();
    ct ^= 1;
  }

  // ---- epilogue ----
  float den = s1;
  den += __shfl_xor(den, 16);
  den += __shfl_xor(den, 32);
  const float iv = 1.f / den;
  float ivr[4];
#pragma unroll
  for (int r = 0; r < 4; ++r) ivr[r] = __shfl(iv, g * 4 + r);
#pragma unroll
  for (int n = 0; n < 4; ++n)
#pragma unroll
    for (int r = 0; r < 4; ++r) {
      const int row = q0w + g * 4 + r;
      const int col = h * 64 + n * 16 + lr;
      y[(size_t)(b * 2048 + row) * 1024 + col] = f2bf(o[n][r] * ivr[r]);
    }
}

// ------------------------------------------------------------------------------------
// ws layout (MB), peak 120:
//   0..24  qkvb | later projP (4 x 8MB, after attn) | later cprojP
//  24..32  h1 (dead after qkv)
//  32..40  wcprojT (written at t=0, read by cproj)
//  48..64  x1 (f32)
//  64..72  yb (attn out) | h2 (reduce_ln out, after proj)
//  72..80  vT (dead before hf) | 72..104 hf
// 104..112 wattnT(6)+wprojT(2)
// 112..120 wfcT
extern "C" void kernel_launch(void* const* d_in, const int* in_sizes, int n_in,
                              void* d_out, int out_size, void* d_ws, size_t ws_size,
                              hipStream_t stream) {
  const float* x      = (const float*)d_in[0];
  const float* ln1w   = (const float*)d_in[1];
  const float* wattn  = (const float*)d_in[2];
  const float* wproj  = (const float*)d_in[3];
  const float* ln2w   = (const float*)d_in[4];
  const float* wfc    = (const float*)d_in[5];
  const float* wcproj = (const float*)d_in[6];
  float* out = (float*)d_out;
  char* ws = (char*)d_ws;
  const size_t MB = 1024 * 1024;
  u16* qkvb    = (u16*)(ws + 0);
  u16* projP   = (u16*)(ws + 0);
  u16* cprojP  = (u16*)(ws + 0);
  u16* h1      = (u16*)(ws + 24 * MB);
  u16* wcprojT = (u16*)(ws + 32 * MB);
  float* x1    = (float*)(ws + 48 * MB);
  u16* yb      = (u16*)(ws + 64 * MB);
  u16* h2      = (u16*)(ws + 64 * MB);
  u16* vT      = (u16*)(ws + 72 * MB);
  u16* hf      = (u16*)(ws + 72 * MB);
  u16* wattnT  = (u16*)(ws + 104 * MB);
  u16* wprojT  = (u16*)(ws + 110 * MB);
  u16* wfcT    = (u16*)(ws + 112 * MB);

  convT_all<<<3072, 256, 0, stream>>>(wattn, wattnT, wproj, wprojT, wfc, wfcT,
                                      wcproj, wcprojT);

  ln_bf16<<<4096, 256, 0, stream>>>(x, ln1w, h1);
  gemm256<0><<<dim3(12, 16, 1), 512, 0, stream>>>(h1, wattnT, qkvb, 4096, 3072, 1024);
  vtrans<<<dim3(32, 32), 256, 0, stream>>>(qkvb, vT);
  attn_fwd<<<dim3(32, 32), 256, 0, stream>>>(qkvb, vT, yb);
  gemm128<4><<<dim3(8, 32, 4), 256, 0, stream>>>(yb, wprojT, projP, 4096, 1024, 1024);
  reduce_ln<<<4096, 256, 0, stream>>>(x, projP, 4, ln2w, x1, h2);
  gemm256<2><<<dim3(16, 16, 1), 512, 0, stream>>>(h2, wfcT, hf, 4096, 4096, 1024);
  gemm256<4><<<dim3(4, 16, 4), 512, 0, stream>>>(hf, wcprojT, cprojP, 4096, 1024, 4096);
  reduce_out<<<4096, 256, 0, stream>>>(x1, cprojP, 4, out);
}

// Round 20
// 221.343 us; speedup vs baseline: 1.0523x; 1.0285x over previous
//
#include <hip/hip_runtime.h>

typedef __attribute__((ext_vector_type(8))) __bf16 bf16x8;
typedef __attribute__((ext_vector_type(4))) float f32x4;
typedef __attribute__((ext_vector_type(8))) unsigned short u16x8;
typedef __attribute__((ext_vector_type(4))) unsigned short u16x4;
typedef unsigned short u16;

__device__ __forceinline__ u16 f2bf(float f) {
  return __builtin_bit_cast(u16, (__bf16)f);
}
__device__ __forceinline__ float bf2f(u16 u) {
  return __builtin_bit_cast(float, ((unsigned)u) << 16);
}

__device__ __forceinline__ f32x4 mfma16(bf16x8 a, bf16x8 b, f32x4 c) {
  return __builtin_amdgcn_mfma_f32_16x16x32_bf16(a, b, c, 0, 0, 0);
}

__device__ __forceinline__ void gl_lds16(const void* g, void* l) {
  __builtin_amdgcn_global_load_lds(
      (const __attribute__((address_space(1))) unsigned int*)g,
      (__attribute__((address_space(3))) unsigned int*)l, 16, 0, 0);
}

__device__ __forceinline__ f32x4 fmax4(f32x4 a, f32x4 b) {
  f32x4 r;
  r[0] = fmaxf(a[0], b[0]); r[1] = fmaxf(a[1], b[1]);
  r[2] = fmaxf(a[2], b[2]); r[3] = fmaxf(a[3], b[3]);
  return r;
}

// ---- prep: LN(x)*w -> h1  PLUS all 4 weight transposes, one launch -----------------
// id layout: [0,4096) ln rows; [4096,4864) wattn; [4864,5120) wproj;
// [5120,6144) wfc; [6144,7168) wcproj. LN first so qkv's h1 dep retires earliest.
__global__ __launch_bounds__(256) void prep(const float* __restrict__ x,
                                            const float* __restrict__ ln1w,
                                            u16* __restrict__ h1,
                                            const float* __restrict__ w0,
                                            u16* __restrict__ o0,
                                            const float* __restrict__ w1,
                                            u16* __restrict__ o1,
                                            const float* __restrict__ w2,
                                            u16* __restrict__ o2,
                                            const float* __restrict__ w3,
                                            u16* __restrict__ o3) {
  __shared__ float tile[64][65];
  __shared__ float sb[8];
  const int id = blockIdx.x;
  const int t = threadIdx.x;
  if (id < 4096) {  // ---- LayerNorm row ----
    const int row = id;
    const float4 v = ((const float4*)(x + (size_t)row * 1024))[t];
    float s = v.x + v.y + v.z + v.w;
    float q = v.x * v.x + v.y * v.y + v.z * v.z + v.w * v.w;
#pragma unroll
    for (int d = 32; d; d >>= 1) { s += __shfl_xor(s, d); q += __shfl_xor(q, d); }
    const int wv = t >> 6;
    if ((t & 63) == 0) { sb[wv] = s; sb[4 + wv] = q; }
    __syncthreads();
    s = sb[0] + sb[1] + sb[2] + sb[3];
    q = sb[4] + sb[5] + sb[6] + sb[7];
    const float mu = s * (1.f / 1024.f);
    const float rstd = rsqrtf(q * (1.f / 1024.f) - mu * mu + 1e-5f);
    const float4 w4 = ((const float4*)ln1w)[t];
    ushort4 o;
    o.x = f2bf((v.x - mu) * rstd * w4.x);
    o.y = f2bf((v.y - mu) * rstd * w4.y);
    o.z = f2bf((v.z - mu) * rstd * w4.z);
    o.w = f2bf((v.w - mu) * rstd * w4.w);
    *(ushort4*)(h1 + (size_t)row * 1024 + t * 4) = o;
    return;
  }
  // ---- transpose+convert job ----
  const float* in;
  u16* outT;
  int K, N, bx, by;
  const int cid = id - 4096;
  if (cid < 768) { in = w0; outT = o0; K = 1024; N = 3072; bx = cid & 15; by = cid >> 4; }
  else if (cid < 1024) { const int j = cid - 768; in = w1; outT = o1; K = 1024; N = 1024; bx = j & 15; by = j >> 4; }
  else if (cid < 2048) { const int j = cid - 1024; in = w2; outT = o2; K = 1024; N = 4096; bx = j & 15; by = j >> 4; }
  else { const int j = cid - 2048; in = w3; outT = o3; K = 4096; N = 1024; bx = j & 63; by = j >> 6; }
  const int tk = bx * 64, tn = by * 64;
  const int lk = t >> 4, ln = (t & 15) * 4;
#pragma unroll
  for (int r = 0; r < 4; ++r) {
    const int k = lk + r * 16;
    const float4 v = *(const float4*)(in + (size_t)(tk + k) * N + tn + ln);
    tile[k][ln + 0] = v.x; tile[k][ln + 1] = v.y;
    tile[k][ln + 2] = v.z; tile[k][ln + 3] = v.w;
  }
  __syncthreads();
  const int sn = t >> 2, sk = (t & 3) * 4;
#pragma unroll
  for (int j = 0; j < 4; ++j) {
    const int k = sk + j * 16;
    ushort4 o;
    o.x = f2bf(tile[k + 0][sn]); o.y = f2bf(tile[k + 1][sn]);
    o.z = f2bf(tile[k + 2][sn]); o.w = f2bf(tile[k + 3][sn]);
    *(ushort4*)(outT + (size_t)(tn + sn) * K + tk + k) = o;
  }
}

// ---- reduce_ln: x1 = x + sum(bf16 partials); h2 = LN(x1)*w. one block per row -------
__global__ __launch_bounds__(256) void reduce_ln(const float* __restrict__ x,
                                                 const u16* __restrict__ p, int nseg,
                                                 const float* __restrict__ wgt,
                                                 float* __restrict__ x1,
                                                 u16* __restrict__ h2) {
  const int row = blockIdx.x, t = threadIdx.x;
  const size_t ro = (size_t)row * 1024 + t * 4;
  float4 v = *(const float4*)(x + ro);
  for (int sgm = 0; sgm < nseg; ++sgm) {
    const ushort4 u = *(const ushort4*)(p + (size_t)sgm * 4096 * 1024 + ro);
    v.x += bf2f(u.x); v.y += bf2f(u.y); v.z += bf2f(u.z); v.w += bf2f(u.w);
  }
  *(float4*)(x1 + ro) = v;
  float s = v.x + v.y + v.z + v.w;
  float q = v.x * v.x + v.y * v.y + v.z * v.z + v.w * v.w;
#pragma unroll
  for (int d = 32; d; d >>= 1) { s += __shfl_xor(s, d); q += __shfl_xor(q, d); }
  __shared__ float sb[8];
  const int wv = t >> 6;
  if ((t & 63) == 0) { sb[wv] = s; sb[4 + wv] = q; }
  __syncthreads();
  s = sb[0] + sb[1] + sb[2] + sb[3];
  q = sb[4] + sb[5] + sb[6] + sb[7];
  const float mu = s * (1.f / 1024.f);
  const float rstd = rsqrtf(q * (1.f / 1024.f) - mu * mu + 1e-5f);
  const float4 w4 = ((const float4*)wgt)[t];
  ushort4 o;
  o.x = f2bf((v.x - mu) * rstd * w4.x);
  o.y = f2bf((v.y - mu) * rstd * w4.y);
  o.z = f2bf((v.z - mu) * rstd * w4.z);
  o.w = f2bf((v.w - mu) * rstd * w4.w);
  *(ushort4*)(h2 + ro) = o;
}

// ---- reduce_out: out = x1 + sum(bf16 partials). one float4 per thread ---------------
__global__ __launch_bounds__(256) void reduce_out(const float* __restrict__ x1,
                                                  const u16* __restrict__ p, int nseg,
                                                  float* __restrict__ out) {
  const int i = blockIdx.x * blockDim.x + threadIdx.x;
  const size_t ro = (size_t)i * 4;
  float4 v = *(const float4*)(x1 + ro);
  for (int sgm = 0; sgm < nseg; ++sgm) {
    const ushort4 u = *(const ushort4*)(p + (size_t)sgm * 4096 * 1024 + ro);
    v.x += bf2f(u.x); v.y += bf2f(u.y); v.z += bf2f(u.z); v.w += bf2f(u.w);
  }
  *(float4*)(out + ro) = v;
}

// ---------------- 128x128 bf16 MFMA GEMM (proj, split-K partials) --------------------
template <int EPI>
__global__ __launch_bounds__(256) void gemm128(const u16* __restrict__ A,
                                               const u16* __restrict__ Bt,
                                               void* __restrict__ outp,
                                               int M, int N, int K) {
  __shared__ u16 As[2][4096];
  __shared__ u16 Bs[2][4096];
  const unsigned gx = gridDim.x, gy = gridDim.y, gxy = gx * gy;
  const unsigned nwg = gxy * gridDim.z;
  unsigned f = (blockIdx.z * gy + blockIdx.y) * gx + blockIdx.x;
  if ((nwg & 7u) == 0u) { const unsigned qq = nwg >> 3; f = (f & 7u) * qq + (f >> 3); }
  const int bx = f % gx, by = (f / gx) % gy, bz = f / gxy;

  const int t = threadIdx.x, w = t >> 6, l = t & 63;
  const int lr = l & 15, g = l >> 4;
  const int row0 = by * 128, col0 = bx * 128;
  const int segK = K / gridDim.z;
  const int k0 = bz * segK, kend = k0 + segK;
  const int wr = w >> 1, wc = w & 1;
  f32x4 acc[4][4] = {};

  const int sr = t >> 2;
  const int sk = (((t & 3) ^ (sr & 3)) << 3);
  const u16* Ag = A + (size_t)(row0 + sr) * K + sk;
  const u16* Bg = Bt + (size_t)(col0 + sr) * K + sk;
  const size_t rstride = (size_t)64 * K;

  auto stage = [&](int kt, int bb) {
    u16* AsW = As[bb] + w * 512;
    u16* BsW = Bs[bb] + w * 512;
    gl_lds16(Ag + kt, AsW);
    gl_lds16(Ag + kt + rstride, AsW + 2048);
    gl_lds16(Bg + kt, BsW);
    gl_lds16(Bg + kt + rstride, BsW + 2048);
  };

  const int gsw = (g ^ (lr & 3)) * 8;

  stage(k0, 0);
  __syncthreads();
  int cur = 0;
  for (int kt = k0; kt < kend; kt += 32) {
    if (kt + 32 < kend) stage(kt + 32, cur ^ 1);
    bf16x8 af[4], bfr[4];
#pragma unroll
    for (int m = 0; m < 4; ++m)
      af[m] = *(const bf16x8*)(As[cur] + (wr * 64 + m * 16 + lr) * 32 + gsw);
#pragma unroll
    for (int n = 0; n < 4; ++n)
      bfr[n] = *(const bf16x8*)(Bs[cur] + (wc * 64 + n * 16 + lr) * 32 + gsw);
#pragma unroll
    for (int m = 0; m < 4; ++m)
#pragma unroll
      for (int n = 0; n < 4; ++n) acc[m][n] = mfma16(af[m], bfr[n], acc[m][n]);
    __syncthreads();
    cur ^= 1;
  }

  const size_t segoff = (size_t)bz * M * N;
#pragma unroll
  for (int m = 0; m < 4; ++m)
#pragma unroll
    for (int n = 0; n < 4; ++n)
#pragma unroll
      for (int r = 0; r < 4; ++r) {
        const int row = row0 + wr * 64 + m * 16 + g * 4 + r;
        const int col = col0 + wc * 64 + n * 16 + lr;
        const size_t idx = (size_t)row * N + col;
        const float v = acc[m][n][r];
        if constexpr (EPI == 0) ((u16*)outp)[idx] = f2bf(v);
        else if constexpr (EPI == 2) ((u16*)outp)[idx] = f2bf(fmaxf(v, 0.f));
        else ((u16*)outp)[segoff + idx] = f2bf(v);
      }
}

// ---------------- 256x256 8-phase bf16 GEMM — R15 discipline -------------------------
// EPI 0: bf16 ; EPI 2: relu bf16 ; EPI 4: bf16 partial at seg bz ;
// EPI 5 (qkv): Q/K quadrants -> bf16 to outp; V quadrants (col0>=2048) -> LDS-staged
// transpose directly into vT[bh][dh][t] (outp2), replacing the vtrans kernel.
template <int EPI>
__global__ __launch_bounds__(512, 2) void gemm256(const u16* __restrict__ A,
                                                  const u16* __restrict__ Bt,
                                                  u16* __restrict__ outp,
                                                  u16* __restrict__ outp2,
                                                  int M, int N, int K) {
  __shared__ u16 S[2][32768];  // [buf][ A: kh0 0..8191, kh1 8192..16383 | B: +16384 ]
  const unsigned gx = gridDim.x, gy = gridDim.y, gxy = gx * gy;
  const unsigned nwg = gxy * gridDim.z;
  unsigned f = (blockIdx.z * gy + blockIdx.y) * gx + blockIdx.x;
  if ((nwg & 7u) == 0u) { const unsigned qq = nwg >> 3; f = (f & 7u) * qq + (f >> 3); }
  const int bx = f % gx, by = (f / gx) % gy, bz = f / gxy;
  const int t = threadIdx.x, w = t >> 6, l = t & 63;
  const int lr = l & 15, g = l >> 4;
  const int wr = w >> 2, wc = w & 3;
  const int row0 = by * 256, col0 = bx * 256;
  const int segK = K / gridDim.z;
  const int k0 = bz * segK;
  const int NT = segK >> 6;

  f32x4 acc[8][4] = {};

  const int jr0 = t >> 2;
  const int jr1 = jr0 + 128;
  const int jks = ((t & 3) ^ (jr0 & 3)) << 3;
  auto stage_half = [&](int ht, int idx) {
    const int buf = ht & 1;
    u16* db = &S[buf][(idx & 1) * 16384 + (idx >> 1) * 8192 + w * 512];
    const u16* gb = (idx & 1) ? Bt : A;
    const int rc0 = (idx & 1) ? col0 : row0;
    const int kb = k0 + ht * 64 + (idx >> 1) * 32;
    gl_lds16(gb + (size_t)(rc0 + jr0) * K + kb + jks, db);
    gl_lds16(gb + (size_t)(rc0 + jr1) * K + kb + jks, db + 4096);
  };

  const int gsw = (g ^ (lr & 3)) * 8;

  stage_half(0, 0); stage_half(0, 1); stage_half(0, 2); stage_half(0, 3);
  stage_half(1, 0); stage_half(1, 1);
  asm volatile("s_waitcnt vmcnt(4)" ::: "memory");
  __builtin_amdgcn_s_barrier();

  for (int T = 0; T < NT; ++T) {
    const int cur = T & 1;
    const u16* Ab = &S[cur][0];
    const u16* Bb = &S[cur][16384];
    bf16x8 bfr[4];
#pragma unroll
    for (int sub = 0; sub < 4; ++sub) {
      const int mq = sub & 1, ks = sub >> 1;
      if (mq == 0) {
#pragma unroll
        for (int n = 0; n < 4; ++n)
          bfr[n] = *(const bf16x8*)(Bb + ks * 8192 + (wc * 64 + n * 16 + lr) * 32 + gsw);
      }
      bf16x8 af[4];
#pragma unroll
      for (int m = 0; m < 4; ++m)
        af[m] = *(const bf16x8*)(Ab + ks * 8192 +
                                 (wr * 128 + mq * 64 + m * 16 + lr) * 32 + gsw);
      if (sub < 2) { if (T + 1 < NT) stage_half(T + 1, 2 + sub); }
      else         { if (T + 2 < NT) stage_half(T + 2, sub - 2); }
      __builtin_amdgcn_s_barrier();
      __builtin_amdgcn_s_setprio(1);
#pragma unroll
      for (int m = 0; m < 4; ++m)
#pragma unroll
        for (int n = 0; n < 4; ++n)
          acc[mq * 4 + m][n] = mfma16(af[m], bfr[n], acc[mq * 4 + m][n]);
      __builtin_amdgcn_s_setprio(0);
      if (sub == 3) asm volatile("s_waitcnt vmcnt(4)" ::: "memory");
      __builtin_amdgcn_s_barrier();
    }
  }

  if constexpr (EPI == 5) {
    if (col0 >= 2048) {
      // V quadrant: per-wave LDS transpose (XOR-swizzled) -> vT[bh][dh][t]
      __syncthreads();
      u16* Lw = ((u16*)S) + w * 8192;  // 16KB per wave: [64 col][128 row], XOR key
#pragma unroll
      for (int m = 0; m < 8; ++m)
#pragma unroll
        for (int n = 0; n < 4; ++n) {
          const int cl = n * 16 + lr;
          const int rl = m * 16 + g * 4;
          u16x4 pk;
#pragma unroll
          for (int r = 0; r < 4; ++r) pk[r] = f2bf(acc[m][n][r]);
          *(u16x4*)(Lw + cl * 128 + (rl ^ ((cl & 7) << 3))) = pk;
        }
      __syncthreads();
      const int b = row0 >> 11;
      const int tt0w = (row0 & 2047) + wr * 128;
#pragma unroll
      for (int iter = 0; iter < 16; ++iter) {
        const int cl = iter * 4 + (l >> 4);
        const int r8 = (l & 15) * 8;
        const u16x8 vv = *(const u16x8*)(Lw + cl * 128 + (r8 ^ ((cl & 7) << 3)));
        const int col = col0 + wc * 64 + cl;
        const int hh = (col - 2048) >> 6, dh = col & 63;
        *(u16x8*)(outp2 + (((size_t)(b * 16 + hh) * 64 + dh) * 2048 + tt0w + r8)) = vv;
      }
    } else {
      // Q/K quadrants: plain bf16 write
#pragma unroll
      for (int m = 0; m < 8; ++m)
#pragma unroll
        for (int n = 0; n < 4; ++n)
#pragma unroll
          for (int r = 0; r < 4; ++r) {
            const int row = row0 + wr * 128 + m * 16 + g * 4 + r;
            const int col = col0 + wc * 64 + n * 16 + lr;
            outp[(size_t)row * N + col] = f2bf(acc[m][n][r]);
          }
    }
    return;
  }

  const size_t segoff = (size_t)bz * M * N;
#pragma unroll
  for (int m = 0; m < 8; ++m)
#pragma unroll
    for (int n = 0; n < 4; ++n)
#pragma unroll
      for (int r = 0; r < 4; ++r) {
        const int row = row0 + wr * 128 + m * 16 + g * 4 + r;
        const int col = col0 + wc * 64 + n * 16 + lr;
        const size_t idx = (size_t)row * N + col;
        const float v = acc[m][n][r];
        if constexpr (EPI == 0) outp[idx] = f2bf(v);
        else if constexpr (EPI == 2) outp[idx] = f2bf(fmaxf(v, 0.f));
        else outp[segoff + idx] = f2bf(v);
      }
}

// ---------------- causal flash attention, bf16 MFMA (verified config) ----------------
__global__ __launch_bounds__(256) void attn_fwd(const u16* __restrict__ qkvb,
                                                const u16* __restrict__ vT,
                                                u16* __restrict__ y) {
  __shared__ u16 Ks[2][4096];     // 2 x 8KB, swizzled rows [kv][k]
  __shared__ u16 Vs[2][4096];     // 2 x 8KB, swizzled rows [dh][kv]
  __shared__ u16 Pb[4][16 * 64];  // per-wave P: [q 0..15][kv 0..63], XOR-swizzled
  const int t = threadIdx.x, w = t >> 6, l = t & 63;
  const int lr = l & 15, g = l >> 4;
  const unsigned f = blockIdx.y * gridDim.x + blockIdx.x;
  const int xcd = f & 7, j = f >> 3;
  const int bh = xcd + 8 * (j & 3);   // all q-tiles of one bh on one XCD
  const int qt = 31 - (j >> 2);       // descending qt: long blocks dispatch first
  const int b = bh >> 4, h = bh & 15;
  const size_t base = (size_t)b * 2048 * 3072;
  const u16* Kg = qkvb + base + 1024 + h * 64;
  const u16* Vg = vT + (size_t)bh * 64 * 2048;  // [dh][t]
  u16* Pw = &Pb[w][0];
  const int pkey = (lr & 7) << 3;         // P-row XOR key (u16 units)
  const float SCL = 0.0450842200277855f;  // (1/32) * log2(e)

  auto stageK = [&](int kv0, int bb) {
#pragma unroll
    for (int r = 0; r < 2; ++r) {
      const int dl = (r * 256 + t) * 16;
      const int row = dl >> 7;
      const int srcb = (dl & 127) ^ ((row & 7) << 4);
      gl_lds16(Kg + (size_t)(kv0 + row) * 3072 + (srcb >> 1),
               (char*)Ks[bb] + r * 4096 + w * 1024);
    }
  };
  auto stageV = [&](int kv0, int bb) {
#pragma unroll
    for (int r = 0; r < 2; ++r) {
      const int dl = (r * 256 + t) * 16;
      const int dh = dl >> 7;
      const int srcb = (dl & 127) ^ ((dh & 7) << 4);
      gl_lds16(Vg + (size_t)dh * 2048 + kv0 + (srcb >> 1),
               (char*)Vs[bb] + r * 4096 + w * 1024);
    }
  };

  const int q0w = qt * 64 + w * 16, nt = qt + 1;
  const u16* Qp = qkvb + base + (size_t)(q0w + lr) * 3072 + h * 64;
  const bf16x8 qf0 = *(const bf16x8*)(Qp + g * 8);
  const bf16x8 qf1 = *(const bf16x8*)(Qp + 32 + g * 8);
  f32x4 o[4] = {};
  float m1 = -1e30f, s1 = 0.f;  // m1 in SCALED (log2) domain

  stageK(0, 0);
  stageV(0, 0);
  __syncthreads();

  int ct = 0;
  for (int tt = 0; tt < nt; ++tt) {
    const int kv0 = tt * 64;
    if (tt + 1 < nt) {
      stageK(kv0 + 64, ct ^ 1);
      stageV(kv0 + 64, ct ^ 1);
    }

    const u16* Kbuf = Ks[ct];
    const u16* Vbuf = Vs[ct];
    // ---- QK^T swapped (RAW, no scale): s4[i][r] = S[kv0+i*16+g*4+r][q0w+lr] ----
    f32x4 s4[4];
#pragma unroll
    for (int i = 0; i < 4; ++i) {
      const int row = i * 16 + lr;
      const int sw = (row & 7) << 4;
      const bf16x8 k0 = *(const bf16x8*)(Kbuf + row * 64 + (((g * 16) ^ sw) >> 1));
      const bf16x8 k1 = *(const bf16x8*)(Kbuf + row * 64 + (((64 + g * 16) ^ sw) >> 1));
      f32x4 z = {0.f, 0.f, 0.f, 0.f};
      z = mfma16(k0, qf0, z);
      s4[i] = mfma16(k1, qf1, z);
    }
    if (kv0 + 64 > q0w) {  // causal: kv > q
#pragma unroll
      for (int i = 0; i < 4; ++i)
#pragma unroll
        for (int r = 0; r < 4; ++r)
          if (kv0 + i * 16 + g * 4 + r > q0w + lr) s4[i][r] = -1e30f;
    }
    // ---- softmax: raw-domain max tree, single scale; defer-max ----
    const f32x4 mm = fmax4(fmax4(s4[0], s4[1]), fmax4(s4[2], s4[3]));
    float mx = fmaxf(fmaxf(mm[0], mm[1]), fmaxf(mm[2], mm[3]));
    mx = fmaxf(mx, __shfl_xor(mx, 16));
    mx = fmaxf(mx, __shfl_xor(mx, 32));
    const float mxs = mx * SCL;
    if (!__all(mxs <= m1 + 8.f)) {
      const float mn = fmaxf(m1, mxs);
      const float sc = exp2f(m1 - mn);
      m1 = mn;
      s1 *= sc;
      float scr[4];
#pragma unroll
      for (int r = 0; r < 4; ++r) scr[r] = __shfl(sc, g * 4 + r);
#pragma unroll
      for (int n = 0; n < 4; ++n)
#pragma unroll
        for (int r = 0; r < 4; ++r) o[n][r] *= scr[r];
    }
    float ps = 0.f;
#pragma unroll
    for (int i = 0; i < 4; ++i) {
      u16x4 pk;
#pragma unroll
      for (int r = 0; r < 4; ++r) {
        const float p = exp2f(fmaf(s4[i][r], SCL, -m1));
        ps += p;
        pk[r] = f2bf(p);
      }
      *(u16x4*)(Pw + lr * 64 + ((i * 16 + g * 4) ^ pkey)) = pk;
    }
    s1 += ps;
    // ---- PV ----
#pragma unroll
    for (int s = 0; s < 2; ++s) {
      const bf16x8 pa = *(const bf16x8*)(Pw + lr * 64 + ((s * 32 + g * 8) ^ pkey));
#pragma unroll
      for (int n = 0; n < 4; ++n) {
        const int dh = n * 16 + lr;
        const bf16x8 vf = *(const bf16x8*)(
            Vbuf + dh * 64 + (((s * 64 + g * 16) ^ ((dh & 7) << 4)) >> 1));
        o[n] = mfma16(pa, vf, o[n]);
      }
    }
    __syncthreads();
    ct ^= 1;
  }

  // ---- epilogue ----
  float den = s1;
  den += __shfl_xor(den, 16);
  den += __shfl_xor(den, 32);
  const float iv = 1.f / den;
  float ivr[4];
#pragma unroll
  for (int r = 0; r < 4; ++r) ivr[r] = __shfl(iv, g * 4 + r);
#pragma unroll
  for (int n = 0; n < 4; ++n)
#pragma unroll
    for (int r = 0; r < 4; ++r) {
      const int row = q0w + g * 4 + r;
      const int col = h * 64 + n * 16 + lr;
      y[(size_t)(b * 2048 + row) * 1024 + col] = f2bf(o[n][r] * ivr[r]);
    }
}

// ------------------------------------------------------------------------------------
// ws layout (MB), peak 120:
//   0..24  qkvb (V quadrant unused) | later projP (4 x 8MB) | later cprojP
//  24..32  h1 (dead after qkv)
//  32..40  wcprojT
//  48..64  x1 (f32)
//  64..72  yb (attn out) | h2 (reduce_ln out, after proj)
//  72..80  vT (written by qkv epilogue; dead before hf) | 72..104 hf
// 104..112 wattnT(6)+wprojT(2)
// 112..120 wfcT
extern "C" void kernel_launch(void* const* d_in, const int* in_sizes, int n_in,
                              void* d_out, int out_size, void* d_ws, size_t ws_size,
                              hipStream_t stream) {
  const float* x      = (const float*)d_in[0];
  const float* ln1w   = (const float*)d_in[1];
  const float* wattn  = (const float*)d_in[2];
  const float* wproj  = (const float*)d_in[3];
  const float* ln2w   = (const float*)d_in[4];
  const float* wfc    = (const float*)d_in[5];
  const float* wcproj = (const float*)d_in[6];
  float* out = (float*)d_out;
  char* ws = (char*)d_ws;
  const size_t MB = 1024 * 1024;
  u16* qkvb    = (u16*)(ws + 0);
  u16* projP   = (u16*)(ws + 0);
  u16* cprojP  = (u16*)(ws + 0);
  u16* h1      = (u16*)(ws + 24 * MB);
  u16* wcprojT = (u16*)(ws + 32 * MB);
  float* x1    = (float*)(ws + 48 * MB);
  u16* yb      = (u16*)(ws + 64 * MB);
  u16* h2      = (u16*)(ws + 64 * MB);
  u16* vT      = (u16*)(ws + 72 * MB);
  u16* hf      = (u16*)(ws + 72 * MB);
  u16* wattnT  = (u16*)(ws + 104 * MB);
  u16* wprojT  = (u16*)(ws + 110 * MB);
  u16* wfcT    = (u16*)(ws + 112 * MB);

  prep<<<7168, 256, 0, stream>>>(x, ln1w, h1, wattn, wattnT, wproj, wprojT,
                                 wfc, wfcT, wcproj, wcprojT);
  gemm256<5><<<dim3(12, 16, 1), 512, 0, stream>>>(h1, wattnT, qkvb, vT,
                                                  4096, 3072, 1024);
  attn_fwd<<<dim3(32, 32), 256, 0, stream>>>(qkvb, vT, yb);
  gemm128<4><<<dim3(8, 32, 4), 256, 0, stream>>>(yb, wprojT, projP, 4096, 1024, 1024);
  reduce_ln<<<4096, 256, 0, stream>>>(x, projP, 4, ln2w, x1, h2);
  gemm256<2><<<dim3(16, 16, 1), 512, 0, stream>>>(h2, wfcT, hf, nullptr,
                                                  4096, 4096, 1024);
  gemm256<4><<<dim3(4, 16, 4), 512, 0, stream>>>(hf, wcprojT, cprojP, nullptr,
                                                 4096, 1024, 4096);
  reduce_out<<<4096, 256, 0, stream>>>(x1, cprojP, 4, out);
}